// Round 14
// baseline (646.592 us; speedup 1.0000x reference)
//
#include <hip/hip_runtime.h>
#include <math.h>

#define BB 131072
#define HH 64
#define NOB 32
#define NDIRS 8
#define LR_IT 1e-3f
#define TOLV 1e-3f
#define EPSV 1e-6f
#define NBLK 512    // grid for resolve/step/final (1 row/thread)
#define NBF 1024    // grid for fused (2 threads/row)
#define TPB 256
#define WRS 68   // LDS row stride (floats) for Wr / WinT
#define WOS 36   // LDS row stride for WoutT
#define INV_BH (1.0f/8388608.0f)   // 1/(B*H)

// macro params must not be named x/y/z/w (textual expansion vs .x/.y/.z/.w members)
#define D16(pp, Wp, b) ((pp).x*(Wp)[(b)+0] + (pp).y*(Wp)[(b)+1] + (pp).z*(Wp)[(b)+2] + (pp).w*(Wp)[(b)+3])
#define DOT64P(Wp) (D16(p0,Wp,0)+D16(p1,Wp,4)+D16(p2,Wp,8)+D16(p3,Wp,12)+ \
                    D16(p4,Wp,16)+D16(p5,Wp,20)+D16(p6,Wp,24)+D16(p7,Wp,28)+ \
                    D16(p8,Wp,32)+D16(p9,Wp,36)+D16(p10,Wp,40)+D16(p11,Wp,44)+ \
                    D16(p12,Wp,48)+D16(p13,Wp,52)+D16(p14,Wp,56)+D16(p15,Wp,60))
#define DOT32Q(Wp) (D16(q0,Wp,0)+D16(q1,Wp,4)+D16(q2,Wp,8)+D16(q3,Wp,12)+ \
                    D16(q4,Wp,16)+D16(q5,Wp,20)+D16(q6,Wp,24)+D16(q7,Wp,28))
#define LOADP(src) \
  float4 p0=(src)[0], p1=(src)[1], p2=(src)[2], p3=(src)[3], \
         p4=(src)[4], p5=(src)[5], p6=(src)[6], p7=(src)[7], \
         p8=(src)[8], p9=(src)[9], p10=(src)[10], p11=(src)[11], \
         p12=(src)[12], p13=(src)[13], p14=(src)[14], p15=(src)[15];
#define SUMSQ4(pp) ((pp).x*(pp).x + (pp).y*(pp).y + (pp).z*(pp).z + (pp).w*(pp).w)
#define SUM4(pp) ((pp).x + (pp).y + (pp).z + (pp).w)

// ---- LDS staging (stride = blockDim) ----
__device__ __forceinline__ void stage_wr(const float* __restrict__ Wr, float* wrl, int t, int bs) {
  const float4* g = (const float4*)Wr;           // Wr row-major [64][64]
  for (int i = t; i < 1024; i += bs) {
    int h = i >> 4, k4 = i & 15;
    *(float4*)&wrl[h * WRS + k4 * 4] = g[i];
  }
}
__device__ __forceinline__ void stage_wot(const float* __restrict__ Wout, float* wot, int t, int bs) {
  for (int i = t; i < NOB * HH; i += bs) {       // Wout [32][64] -> wot[h][o]
    int o = i >> 6, h = i & 63;
    wot[h * WOS + o] = Wout[i];
  }
}
__device__ __forceinline__ void stage_wint(const float* __restrict__ Win, float* wint, int t, int bs) {
  for (int i = t; i < HH * NDIRS; i += bs) {     // Win [64][8] -> wint[d][h]
    int h = i >> 3, d = i & 7;
    wint[d * WRS + h] = Win[i];
  }
}

// 256-thread block reduction; returns block total to ALL threads.
__device__ __forceinline__ float block_reduce_all(float v, float* red, int t) {
  #pragma unroll
  for (int off = 32; off > 0; off >>= 1) v += __shfl_down(v, off);
  __syncthreads();
  if ((t & 63) == 0) red[t >> 6] = v;
  __syncthreads();
  return red[0] + red[1] + red[2] + red[3];
}

// softmax(a_s * zz) -> jacobian-applied jp, in place
#define SOFTJP(zzp, a_sv, obv) { \
  float m_ = -1e30f; \
  _Pragma("unroll") for (int o_=0;o_<NOB;++o_) m_ = fmaxf(m_, (zzp)[o_]); \
  float se_ = 0.f; \
  _Pragma("unroll") for (int o_=0;o_<NOB;++o_){ (zzp)[o_]=__expf((a_sv)*((zzp)[o_]-m_)); se_+=(zzp)[o_];} \
  float rse_ = 1.f/se_; float fob_=0.f, sf2_=0.f; \
  _Pragma("unroll") for (int o_=0;o_<NOB;++o_){ float f_=(zzp)[o_]*rse_; (zzp)[o_]=f_; sf2_+=f_*f_; fob_ += (o_==(obv))?f_:0.f;} \
  float fe_ = fob_ - sf2_; \
  _Pragma("unroll") for (int o_=0;o_<NOB;++o_){ float ep_=((o_==(obv))?1.f:0.f)-(zzp)[o_]; (zzp)[o_]=(zzp)[o_]*(ep_-fe_);} }

// preds = softmax(a_s * S_raw @ wot) -> out[:B*32]; a_s*S_raw -> out[B*32:]
__device__ __forceinline__ void final_write(
    int r, float a_s, const float* __restrict__ S, float* __restrict__ out,
    const float* wot) {
  const float4* __restrict__ sr4 = (const float4*)(S + (size_t)r * HH);
  float zz[NOB];
  #pragma unroll
  for (int o = 0; o < NOB; ++o) zz[o] = 0.f;
  #pragma unroll 1
  for (int h0 = 0; h0 < 16; ++h0) {
    float4 s4 = sr4[h0];
    const float* t0 = &wot[(h0 * 4 + 0) * WOS];
    const float* t1 = &wot[(h0 * 4 + 1) * WOS];
    const float* t2 = &wot[(h0 * 4 + 2) * WOS];
    const float* t3 = &wot[(h0 * 4 + 3) * WOS];
    #pragma unroll
    for (int o = 0; o < NOB; ++o)
      zz[o] += s4.x * t0[o] + s4.y * t1[o] + s4.z * t2[o] + s4.w * t3[o];
  }
  float m = -1e30f;
  #pragma unroll
  for (int o = 0; o < NOB; ++o) m = fmaxf(m, zz[o]);
  float se = 0.f;
  #pragma unroll
  for (int o = 0; o < NOB; ++o) { zz[o] = __expf(a_s * (zz[o] - m)); se += zz[o]; }
  float rse = 1.f / se;

  float4* po = (float4*)(out + (size_t)r * NOB);
  #pragma unroll
  for (int o4 = 0; o4 < 8; ++o4) {
    float4 f;
    f.x = zz[o4 * 4 + 0] * rse; f.y = zz[o4 * 4 + 1] * rse;
    f.z = zz[o4 * 4 + 2] * rse; f.w = zz[o4 * 4 + 3] * rse;
    po[o4] = f;
  }
  float4* so = (float4*)(out + (size_t)BB * NOB + (size_t)r * HH);
  #pragma unroll 1
  for (int h0 = 0; h0 < 16; ++h0) {
    float4 s4 = sr4[h0];
    s4.x *= a_s; s4.y *= a_s; s4.z *= a_s; s4.w *= a_s;
    so[h0] = s4;
  }
}

// ---- fused: init + iteration-0, 2 THREADS PER ROW (split-K / split-H) ----
// Even lane owns k,h in [0,32); odd lane [32,64). Partials combined via shfl_xor(1).
__global__ __launch_bounds__(TPB, 4) void fused_kernel(
    const float* __restrict__ x, const int* __restrict__ dirs,
    const int* __restrict__ obs,
    const float* __restrict__ Wr, const float* __restrict__ Win,
    const float* __restrict__ Wout,
    float* __restrict__ buf0, float* __restrict__ buf1,
    float* __restrict__ scl0, float* __restrict__ scl1,
    float* __restrict__ partials0, float* __restrict__ partials1)
{
  __shared__ float wrl[HH * WRS];
  __shared__ float wot[HH * WOS];
  __shared__ float wint[NDIRS * WRS];
  __shared__ float red[4];
  int t = threadIdx.x;
  stage_wr(Wr, wrl, t, TPB);
  stage_wot(Wout, wot, t, TPB);
  stage_wint(Win, wint, t, TPB);
  __syncthreads();

  int gid = blockIdx.x * TPB + t;
  int r = gid >> 1;          // row
  int half = gid & 1;        // 0: k/h in [0,32), 1: [32,64)
  int kbase = half << 5;

  int dir = dirs[r];
  int ob = obs[r];

  // ---- pass 1: x half-row in regs; full s0 via pair-combine ----
  const float4* __restrict__ xr = (const float4*)(x + (size_t)r * HH + kbase);
  float4 q0=xr[0],q1=xr[1],q2=xr[2],q3=xr[3],q4=xr[4],q5=xr[5],q6=xr[6],q7=xr[7];
  float ssx_h = SUMSQ4(q0)+SUMSQ4(q1)+SUMSQ4(q2)+SUMSQ4(q3)+SUMSQ4(q4)+SUMSQ4(q5)+SUMSQ4(q6)+SUMSQ4(q7);
  float sx_h  = SUM4(q0)+SUM4(q1)+SUM4(q2)+SUM4(q3)+SUM4(q4)+SUM4(q5)+SUM4(q6)+SUM4(q7);
  float ssx = ssx_h + __shfl_xor(ssx_h, 1);
  float sx  = sx_h  + __shfl_xor(sx_h, 1);
  float inv_x = 1.f / (sqrtf(ssx) + EPSV);

  float4 m[8];               // my 32 raw s0 values (own h-half), static-indexed
  float4* bo = (float4*)(buf0 + (size_t)r * HH + kbase);
  float ssg_h = 0.f, sg_h = 0.f;
  #pragma unroll
  for (int c = 0; c < 8; ++c) {
    float4 pL, pH;           // partial dots over MY k-half, for h-chunks c and c+8
    pL.x = DOT32Q(&wrl[(c*4+0)*WRS + kbase]);
    pL.y = DOT32Q(&wrl[(c*4+1)*WRS + kbase]);
    pL.z = DOT32Q(&wrl[(c*4+2)*WRS + kbase]);
    pL.w = DOT32Q(&wrl[(c*4+3)*WRS + kbase]);
    pH.x = DOT32Q(&wrl[(32+c*4+0)*WRS + kbase]);
    pH.y = DOT32Q(&wrl[(32+c*4+1)*WRS + kbase]);
    pH.z = DOT32Q(&wrl[(32+c*4+2)*WRS + kbase]);
    pH.w = DOT32Q(&wrl[(32+c*4+3)*WRS + kbase]);
    pL.x += __shfl_xor(pL.x, 1); pL.y += __shfl_xor(pL.y, 1);
    pL.z += __shfl_xor(pL.z, 1); pL.w += __shfl_xor(pL.w, 1);
    pH.x += __shfl_xor(pH.x, 1); pH.y += __shfl_xor(pH.y, 1);
    pH.z += __shfl_xor(pH.z, 1); pH.w += __shfl_xor(pH.w, 1);
    float4 p;                // my own h-chunk's full dot
    p.x = half ? pH.x : pL.x; p.y = half ? pH.y : pL.y;
    p.z = half ? pH.z : pL.z; p.w = half ? pH.w : pL.w;
    float4 d4 = *(const float4*)&wint[dir * WRS + kbase + c * 4];
    float4 u;
    u.x = fmaxf(fmaf(inv_x, p.x, d4.x), 0.f);
    u.y = fmaxf(fmaf(inv_x, p.y, d4.y), 0.f);
    u.z = fmaxf(fmaf(inv_x, p.z, d4.z), 0.f);
    u.w = fmaxf(fmaf(inv_x, p.w, d4.w), 0.f);
    m[c] = u;
    bo[c] = u;
    ssg_h += SUMSQ4(u); sg_h += SUM4(u);
  }
  float ssg = ssg_h + __shfl_xor(ssg_h, 1);
  float sg  = sg_h  + __shfl_xor(sg_h, 1);
  float inv_g = 1.f / (sqrtf(ssg) + EPSV);
  if (!half) scl0[r] = inv_g;
  float a_s = inv_g;
  float gate0 = inv_x * sx - inv_g * sg;

  __syncthreads();   // live-range firewall: q regs die here

  // ---- pass 2: logits (partial over own h's, pair-combined), softmax/jp, phase C ----
  float zz[NOB];
  #pragma unroll
  for (int o = 0; o < NOB; ++o) zz[o] = 0.f;
  #pragma unroll
  for (int c = 0; c < 8; ++c) {
    int hb = kbase + c * 4;
    const float* t0 = &wot[(hb + 0) * WOS];
    const float* t1 = &wot[(hb + 1) * WOS];
    const float* t2 = &wot[(hb + 2) * WOS];
    const float* t3 = &wot[(hb + 3) * WOS];
    #pragma unroll
    for (int o = 0; o < NOB; ++o)
      zz[o] += m[c].x * t0[o] + m[c].y * t1[o] + m[c].z * t2[o] + m[c].w * t3[o];
  }
  #pragma unroll
  for (int o = 0; o < NOB; ++o) zz[o] += __shfl_xor(zz[o], 1);   // full logits (both lanes)

  SOFTJP(zz, a_s, ob)

  // phase C: g == raw s0 (iteration-0 identity); u = s + LR*(g - s + jp@Wout)
  float4* wo4 = (float4*)(buf1 + (size_t)r * HH + kbase);
  float ssu_h = 0.f, su_h = 0.f;
#define PC_ONE(JJ, COMP) { \
    const float* wt_ = &wot[(hb + JJ) * WOS]; \
    float w_ = 0.f; \
    _Pragma("unroll") \
    for (int o = 0; o < NOB; ++o) w_ += zz[o] * wt_[o]; \
    float g_ = m[c].COMP; \
    float sv_ = a_s * g_; \
    float uu_ = fmaf(LR_IT, g_ - sv_ + w_, sv_); \
    u4.COMP = uu_; ssu_h += uu_ * uu_; su_h += uu_; }
  #pragma unroll
  for (int c = 0; c < 8; ++c) {
    int hb = kbase + c * 4;
    float4 u4;
    PC_ONE(0, x) PC_ONE(1, y) PC_ONE(2, z) PC_ONE(3, w)
    wo4[c] = u4;
  }
  float ssu = ssu_h + __shfl_xor(ssu_h, 1);
  float su  = su_h  + __shfl_xor(su_h, 1);
  float inv_u = 1.f / (sqrtf(ssu) + EPSV);
  if (!half) scl1[r] = inv_u;
  float gate1 = a_s * sg - inv_u * su;

  float tot0 = block_reduce_all(half ? 0.f : gate0, red, t);
  if (t == 0) partials0[blockIdx.x] = tot0;
  float tot1 = block_reduce_all(half ? 0.f : gate1, red, t);
  if (t == 0) partials1[blockIdx.x] = tot1;
}

// gate reduce over the NBF(=1024)-entry partials array, 256 threads
__device__ __forceinline__ float gate_reduce(const float* __restrict__ p, float* red, int t) {
  float v = p[t] + p[t + 256] + p[t + 512] + p[t + 768];
  return block_reduce_all(v, red, t);
}

// ---- resolve: decide act0/act1 (grid-uniform), expected path writes output ----
__global__ __launch_bounds__(TPB, 2) void resolve_kernel(
    float* __restrict__ buf0, float* __restrict__ buf1,
    float* __restrict__ scl0, float* __restrict__ scl1,
    const float* __restrict__ Wr, const float* __restrict__ Wout,
    const float* __restrict__ Win,
    const int* __restrict__ dirs, const int* __restrict__ obs,
    const float* __restrict__ partials0, float* __restrict__ partials,
    int* __restrict__ actArr, float* __restrict__ out)
{
  __shared__ float wrl[HH * WRS];
  __shared__ float wot[HH * WOS];
  __shared__ float wint[NDIRS * WRS];
  __shared__ float red[4];
  int t = threadIdx.x;

  float t0v = gate_reduce(partials0, red, t);
  int act0 = (fabsf(t0v * INV_BH) > TOLV) ? 1 : 0;
  float t1v = gate_reduce(partials, red, t);
  int act1 = (fabsf(t1v * INV_BH) > TOLV) ? 1 : 0;
  if (blockIdx.x == 0 && t == 0) actArr[1] = act0 && act1;

  int r = blockIdx.x * TPB + t;

  if (!act0) {
    // iteration 0 inactive: final = s0. Keep sticky invariant over all NBF entries.
    if (t == 0) {
      partials[blockIdx.x] = partials0[blockIdx.x];
      partials[blockIdx.x + NBLK] = partials0[blockIdx.x + NBLK];
    }
    stage_wot(Wout, wot, t, TPB);
    __syncthreads();
    final_write(r, scl0[r], buf0, out, wot);
    return;
  }
  if (!act1) {
    // expected path: iteration 1 inactive: final = s1 (buf1 is the out s-slice).
    stage_wot(Wout, wot, t, TPB);
    __syncthreads();
    final_write(r, scl1[r], buf1, out, wot);
    return;
  }

  // both active: run iteration 1 fully. S=buf1/scl1, P=buf0 (scl0), W=buf0/scl0.
  stage_wr(Wr, wrl, t, TPB);
  stage_wot(Wout, wot, t, TPB);
  stage_wint(Win, wint, t, TPB);
  __syncthreads();

  float a_s = scl1[r];
  float a_p = scl0[r];
  int ob = obs[r];
  int dir = dirs[r];
  const float4* __restrict__ sr4 = (const float4*)(buf1 + (size_t)r * HH);

  float zz[NOB];
  #pragma unroll
  for (int o = 0; o < NOB; ++o) zz[o] = 0.f;
  float sS = 0.f;
  #pragma unroll 1
  for (int h0 = 0; h0 < 16; ++h0) {
    float4 s4 = sr4[h0];
    sS += SUM4(s4);
    const float* t0 = &wot[(h0 * 4 + 0) * WOS];
    const float* t1 = &wot[(h0 * 4 + 1) * WOS];
    const float* t2 = &wot[(h0 * 4 + 2) * WOS];
    const float* t3 = &wot[(h0 * 4 + 3) * WOS];
    #pragma unroll
    for (int o = 0; o < NOB; ++o)
      zz[o] += s4.x * t0[o] + s4.y * t1[o] + s4.z * t2[o] + s4.w * t3[o];
  }
  SOFTJP(zz, a_s, ob)
  __syncthreads();   // live-range firewall

  const float4* __restrict__ pr4 = (const float4*)(buf0 + (size_t)r * HH);
  LOADP(pr4);
  float4* wo4 = (float4*)(buf0 + (size_t)r * HH);
  float ssu = 0.f, su = 0.f;
#define STEP_C_ONE(JJ, COMP) { \
    const float* wr_ = &wrl[(h0 * 4 + JJ) * WRS]; \
    float g_ = fmaxf(fmaf(a_p, DOT64P(wr_), d4.COMP), 0.f); \
    const float* wt_ = &wot[(h0 * 4 + JJ) * WOS]; \
    float w_ = 0.f; \
    _Pragma("unroll") \
    for (int o = 0; o < NOB; ++o) w_ += zz[o] * wt_[o]; \
    float sv_ = a_s * s4.COMP; \
    float uu_ = fmaf(LR_IT, g_ - sv_ + w_, sv_); \
    u.COMP = uu_; ssu += uu_ * uu_; su += uu_; }
  #pragma unroll 1
  for (int h0 = 0; h0 < 16; ++h0) {
    float4 s4 = sr4[h0];
    float4 d4 = *(const float4*)&wint[dir * WRS + h0 * 4];
    float4 u;
    STEP_C_ONE(0, x) STEP_C_ONE(1, y) STEP_C_ONE(2, z) STEP_C_ONE(3, w)
    wo4[h0] = u;
  }
  float inv_u = 1.f / (sqrtf(ssu) + EPSV);
  scl0[r] = inv_u;

  float tot2 = block_reduce_all(a_s * sS - inv_u * su, red, t);
  if (t == 0) partials[blockIdx.x] = tot2;
  if (t == 1) partials[blockIdx.x + NBLK] = 0.f;   // unused upper half: keep <= tol
}

// ---- generic step k>=2: gate + (active | first-inactive final | no-op) ----
__global__ __launch_bounds__(TPB, 2) void step_kernel(
    float* __restrict__ buf0, float* __restrict__ buf1,
    float* __restrict__ scl0, float* __restrict__ scl1,
    const float* __restrict__ Wr, const float* __restrict__ Wout,
    const float* __restrict__ Win,
    const int* __restrict__ dirs, const int* __restrict__ obs,
    float* __restrict__ partials, int* __restrict__ actArr,
    float* __restrict__ out, int k)
{
  __shared__ float red[4];
  __shared__ float wrl[HH * WRS];
  __shared__ float wot[HH * WOS];
  __shared__ float wint[NDIRS * WRS];
  int t = threadIdx.x;

  float tot = gate_reduce(partials, red, t);
  int active = (fabsf(tot * INV_BH) > TOLV) ? 1 : 0;
  if (blockIdx.x == 0 && t == 0) actArr[k] = active;

  int si = k & 1;
  int r = blockIdx.x * TPB + t;

  if (!active) {
    int first_inactive = actArr[k - 1];   // written by previous launch
    if (!first_inactive) return;          // uniform across grid
    stage_wot(Wout, wot, t, TPB);
    __syncthreads();
    const float* S   = si ? buf1 : buf0;
    const float* scl = si ? scl1 : scl0;
    final_write(r, scl[r], S, out, wot);
    return;
  }

  const float* S    = si ? buf1 : buf0;
  const float* sclS = si ? scl1 : scl0;
  float* W          = si ? buf0 : buf1;
  float* sclW       = si ? scl0 : scl1;

  stage_wr(Wr, wrl, t, TPB);
  stage_wot(Wout, wot, t, TPB);
  stage_wint(Win, wint, t, TPB);
  __syncthreads();

  float a_s = sclS[r];
  float a_p = sclW[r];
  int ob = obs[r];
  int dir = dirs[r];
  const float4* __restrict__ sr4 = (const float4*)(S + (size_t)r * HH);

  float zz[NOB];
  #pragma unroll
  for (int o = 0; o < NOB; ++o) zz[o] = 0.f;
  float sS = 0.f;
  #pragma unroll 1
  for (int h0 = 0; h0 < 16; ++h0) {
    float4 s4 = sr4[h0];
    sS += SUM4(s4);
    const float* t0 = &wot[(h0 * 4 + 0) * WOS];
    const float* t1 = &wot[(h0 * 4 + 1) * WOS];
    const float* t2 = &wot[(h0 * 4 + 2) * WOS];
    const float* t3 = &wot[(h0 * 4 + 3) * WOS];
    #pragma unroll
    for (int o = 0; o < NOB; ++o)
      zz[o] += s4.x * t0[o] + s4.y * t1[o] + s4.z * t2[o] + s4.w * t3[o];
  }
  SOFTJP(zz, a_s, ob)
  __syncthreads();   // live-range firewall

  const float4* __restrict__ pr4 = (const float4*)(W + (size_t)r * HH);
  LOADP(pr4);
  float4* wo4 = (float4*)(W + (size_t)r * HH);
  float ssu = 0.f, su = 0.f;
  #pragma unroll 1
  for (int h0 = 0; h0 < 16; ++h0) {
    float4 s4 = sr4[h0];
    float4 d4 = *(const float4*)&wint[dir * WRS + h0 * 4];
    float4 u;
    STEP_C_ONE(0, x) STEP_C_ONE(1, y) STEP_C_ONE(2, z) STEP_C_ONE(3, w)
    wo4[h0] = u;
  }
  float inv_u = 1.f / (sqrtf(ssu) + EPSV);
  sclW[r] = inv_u;

  float tot2 = block_reduce_all(a_s * sS - inv_u * su, red, t);
  if (t == 0) partials[blockIdx.x] = tot2;
  if (t == 1) partials[blockIdx.x + NBLK] = 0.f;
}

// ---- tail: only fires when all 10 iterations were active ----
__global__ __launch_bounds__(TPB, 2) void final_kernel(
    const float* __restrict__ buf0, float* __restrict__ out,
    const float* __restrict__ scl0,
    const float* __restrict__ Wout, const int* __restrict__ actArr)
{
  if (actArr[9] == 0) return;
  __shared__ float wot[HH * WOS];
  int t = threadIdx.x;
  stage_wot(Wout, wot, t, TPB);
  __syncthreads();
  int r = blockIdx.x * TPB + t;   // 10 active iterations: s10 in buf0/scl0
  final_write(r, scl0[r], buf0, out, wot);
}

extern "C" void kernel_launch(void* const* d_in, const int* in_sizes, int n_in,
                              void* d_out, int out_size, void* d_ws, size_t ws_size,
                              hipStream_t stream) {
  const int* dirs = (const int*)d_in[0];
  const int* obs = (const int*)d_in[1];
  const float* x = (const float*)d_in[2];
  const float* Wr = (const float*)d_in[3];
  const float* Win = (const float*)d_in[4];
  const float* Wout = (const float*)d_in[5];
  float* out = (float*)d_out;
  float* ws = (float*)d_ws;

  float* buf0 = ws;                              // B*H raw state s0 (then s2,..)
  float* scl0 = ws + (size_t)BB * HH;            // B
  float* scl1 = scl0 + BB;                       // B
  float* partials = scl1 + BB;                   // NBF (gate for "current" iteration)
  float* partials0 = partials + NBF;             // NBF (gate0)
  int* actArr = (int*)(partials0 + NBF);         // 16 ints
  float* buf1 = out + (size_t)BB * NOB;          // s-slice of d_out: s1 (then s3,..)

  fused_kernel<<<NBF, TPB, 0, stream>>>(x, dirs, obs, Wr, Win, Wout,
                                        buf0, buf1, scl0, scl1, partials0, partials);
  resolve_kernel<<<NBLK, TPB, 0, stream>>>(buf0, buf1, scl0, scl1, Wr, Wout, Win,
                                           dirs, obs, partials0, partials, actArr, out);
  for (int k = 2; k < 10; ++k)
    step_kernel<<<NBLK, TPB, 0, stream>>>(buf0, buf1, scl0, scl1,
                                          Wr, Wout, Win, dirs, obs, partials, actArr, out, k);
  final_kernel<<<NBLK, TPB, 0, stream>>>(buf0, out, scl0, Wout, actArr);
}

// Round 17
// 190.049 us; speedup vs baseline: 3.4022x; 3.4022x over previous
//
#include <hip/hip_runtime.h>
#include <math.h>

#define BB 131072
#define HH 64
#define NOB 32
#define NDIRS 8
#define LR_IT 1e-3f
#define TOLV 1e-3f
#define EPSV 1e-6f
#define NBLK 512
#define TPB 256
#define WRS 68   // LDS row stride for Wr / WinT (legacy kernels only)
#define WOS 36   // LDS row stride for WoutT (legacy kernels only)
#define INV_BH (1.0f/8388608.0f)   // 1/(B*H)

typedef __attribute__((ext_vector_type(16))) float f32x16;

// Load 32 uniform floats into SGPRs through the scalar pipe. The waitcnt MUST
// be inside the same asm (SMEM may return out-of-order; consumers depend on
// the asm outputs, so the data dependency is honored).
#define SLOAD32(dA, dB, uptr) \
  asm volatile("s_load_dwordx16 %0, %2, 0x0\n\t" \
               "s_load_dwordx16 %1, %2, 0x40\n\t" \
               "s_waitcnt lgkmcnt(0)" \
               : "=s"(dA), "=s"(dB) : "s"(uptr));

// macro params must not be named x/y/z/w (textual expansion vs .x/.y/.z/.w members)
#define D16(pp, Wp, b) ((pp).x*(Wp)[(b)+0] + (pp).y*(Wp)[(b)+1] + (pp).z*(Wp)[(b)+2] + (pp).w*(Wp)[(b)+3])
#define DOT64P(Wp) (D16(p0,Wp,0)+D16(p1,Wp,4)+D16(p2,Wp,8)+D16(p3,Wp,12)+ \
                    D16(p4,Wp,16)+D16(p5,Wp,20)+D16(p6,Wp,24)+D16(p7,Wp,28)+ \
                    D16(p8,Wp,32)+D16(p9,Wp,36)+D16(p10,Wp,40)+D16(p11,Wp,44)+ \
                    D16(p12,Wp,48)+D16(p13,Wp,52)+D16(p14,Wp,56)+D16(p15,Wp,60))
// dot of 4 float4 VGPR chunks with a 16-float SGPR vector
#define DSG4(pp, wv, b) ((pp).x*(wv)[(b)+0] + (pp).y*(wv)[(b)+1] + (pp).z*(wv)[(b)+2] + (pp).w*(wv)[(b)+3])
#define DOTQ(pa, pb, pc, pd, wv) (DSG4(pa,wv,0)+DSG4(pb,wv,4)+DSG4(pc,wv,8)+DSG4(pd,wv,12))
// dot of zz[32] (VGPR, constant indices) with two 16-float SGPR vectors
#define DOTZZ(wA, wB) ({ float s_=0.f; \
  _Pragma("unroll") for (int i_=0;i_<16;++i_) s_ += zz[i_]*(wA)[i_]; \
  _Pragma("unroll") for (int i_=0;i_<16;++i_) s_ += zz[16+i_]*(wB)[i_]; s_; })

#define LOADP(src) \
  float4 p0=(src)[0], p1=(src)[1], p2=(src)[2], p3=(src)[3], \
         p4=(src)[4], p5=(src)[5], p6=(src)[6], p7=(src)[7], \
         p8=(src)[8], p9=(src)[9], p10=(src)[10], p11=(src)[11], \
         p12=(src)[12], p13=(src)[13], p14=(src)[14], p15=(src)[15];
#define SUMSQ4(pp) ((pp).x*(pp).x + (pp).y*(pp).y + (pp).z*(pp).z + (pp).w*(pp).w)
#define SUM4(pp) ((pp).x + (pp).y + (pp).z + (pp).w)

// ---- LDS staging (legacy kernels: resolve/step/final) ----
__device__ __forceinline__ void stage_wr(const float* __restrict__ Wr, float* wrl, int t, int bs) {
  const float4* g = (const float4*)Wr;
  for (int i = t; i < 1024; i += bs) {
    int h = i >> 4, k4 = i & 15;
    *(float4*)&wrl[h * WRS + k4 * 4] = g[i];
  }
}
__device__ __forceinline__ void stage_wot(const float* __restrict__ Wout, float* wot, int t, int bs) {
  for (int i = t; i < NOB * HH; i += bs) {
    int o = i >> 6, h = i & 63;
    wot[h * WOS + o] = Wout[i];
  }
}
__device__ __forceinline__ void stage_wint(const float* __restrict__ Win, float* wint, int t, int bs) {
  for (int i = t; i < HH * NDIRS; i += bs) {
    int h = i >> 3, d = i & 7;
    wint[d * WRS + h] = Win[i];
  }
}

__device__ __forceinline__ float block_reduce_all(float v, float* red, int t) {
  #pragma unroll
  for (int off = 32; off > 0; off >>= 1) v += __shfl_down(v, off);
  __syncthreads();
  if ((t & 63) == 0) red[t >> 6] = v;
  __syncthreads();
  return red[0] + red[1] + red[2] + red[3];
}

#define SOFTJP(zzp, a_sv, obv) { \
  float m_ = -1e30f; \
  _Pragma("unroll") for (int o_=0;o_<NOB;++o_) m_ = fmaxf(m_, (zzp)[o_]); \
  float se_ = 0.f; \
  _Pragma("unroll") for (int o_=0;o_<NOB;++o_){ (zzp)[o_]=__expf((a_sv)*((zzp)[o_]-m_)); se_+=(zzp)[o_];} \
  float rse_ = 1.f/se_; float fob_=0.f, sf2_=0.f; \
  _Pragma("unroll") for (int o_=0;o_<NOB;++o_){ float f_=(zzp)[o_]*rse_; (zzp)[o_]=f_; sf2_+=f_*f_; fob_ += (o_==(obv))?f_:0.f;} \
  float fe_ = fob_ - sf2_; \
  _Pragma("unroll") for (int o_=0;o_<NOB;++o_){ float ep_=((o_==(obv))?1.f:0.f)-(zzp)[o_]; (zzp)[o_]=(zzp)[o_]*(ep_-fe_);} }

// preds -> out[:B*32]; a_s*S_raw -> out[B*32:]   (legacy LDS-wot form)
__device__ __forceinline__ void final_write(
    int r, float a_s, const float* __restrict__ S, float* __restrict__ out,
    const float* wot) {
  const float4* __restrict__ sr4 = (const float4*)(S + (size_t)r * HH);
  float zz[NOB];
  #pragma unroll
  for (int o = 0; o < NOB; ++o) zz[o] = 0.f;
  #pragma unroll 1
  for (int h0 = 0; h0 < 16; ++h0) {
    float4 s4 = sr4[h0];
    const float* t0 = &wot[(h0 * 4 + 0) * WOS];
    const float* t1 = &wot[(h0 * 4 + 1) * WOS];
    const float* t2 = &wot[(h0 * 4 + 2) * WOS];
    const float* t3 = &wot[(h0 * 4 + 3) * WOS];
    #pragma unroll
    for (int o = 0; o < NOB; ++o)
      zz[o] += s4.x * t0[o] + s4.y * t1[o] + s4.z * t2[o] + s4.w * t3[o];
  }
  float m = -1e30f;
  #pragma unroll
  for (int o = 0; o < NOB; ++o) m = fmaxf(m, zz[o]);
  float se = 0.f;
  #pragma unroll
  for (int o = 0; o < NOB; ++o) { zz[o] = __expf(a_s * (zz[o] - m)); se += zz[o]; }
  float rse = 1.f / se;

  float4* po = (float4*)(out + (size_t)r * NOB);
  #pragma unroll
  for (int o4 = 0; o4 < 8; ++o4) {
    float4 f;
    f.x = zz[o4 * 4 + 0] * rse; f.y = zz[o4 * 4 + 1] * rse;
    f.z = zz[o4 * 4 + 2] * rse; f.w = zz[o4 * 4 + 3] * rse;
    po[o4] = f;
  }
  float4* so = (float4*)(out + (size_t)BB * NOB + (size_t)r * HH);
  #pragma unroll 1
  for (int h0 = 0; h0 < 16; ++h0) {
    float4 s4 = sr4[h0];
    s4.x *= a_s; s4.y *= a_s; s4.z *= a_s; s4.w *= a_s;
    so[h0] = s4;
  }
}

// ---- prep: wotT[h][o] = Wout[o][h]; winT[d][h] = Win[h][d] ----
__global__ __launch_bounds__(TPB) void prep_kernel(
    const float* __restrict__ Wout, const float* __restrict__ Win,
    float* __restrict__ wotT, float* __restrict__ winT)
{
  int t = threadIdx.x;
  for (int i = t; i < NOB * HH; i += TPB) { int h = i >> 5, o = i & 31; wotT[i] = Wout[o * HH + h]; }
  for (int i = t; i < NDIRS * HH; i += TPB) { int d = i >> 6, h = i & 63; winT[i] = Win[h * NDIRS + d]; }
}

// ---- fused: init + iteration-0 candidate; ALL weights via scalar s_load ----
__global__ __launch_bounds__(TPB, 2) void fused_kernel(
    const float* __restrict__ x, const int* __restrict__ dirs,
    const int* __restrict__ obs,
    const float* __restrict__ Wr, const float* __restrict__ Wout,
    const float* __restrict__ wotT, const float* __restrict__ winT,
    float* __restrict__ buf0, float* __restrict__ buf1,
    float* __restrict__ scl0, float* __restrict__ scl1,
    float* __restrict__ partials0, float* __restrict__ partials1)
{
  __shared__ float red[4];
  int t = threadIdx.x;
  int r = blockIdx.x * TPB + t;
  float gate0, a_s, sg;
  int dir = dirs[r];
  int ob = obs[r];

  // ---- pass 1: x row in regs; s0 = relu(inv_x * x@WrT + drive); Wr via SGPR ----
  {
    const float4* __restrict__ xr = (const float4*)(x + (size_t)r * HH);
    LOADP(xr);
    float ssx = SUMSQ4(p0)+SUMSQ4(p1)+SUMSQ4(p2)+SUMSQ4(p3)+SUMSQ4(p4)+SUMSQ4(p5)+
                SUMSQ4(p6)+SUMSQ4(p7)+SUMSQ4(p8)+SUMSQ4(p9)+SUMSQ4(p10)+SUMSQ4(p11)+
                SUMSQ4(p12)+SUMSQ4(p13)+SUMSQ4(p14)+SUMSQ4(p15);
    float sx  = SUM4(p0)+SUM4(p1)+SUM4(p2)+SUM4(p3)+SUM4(p4)+SUM4(p5)+SUM4(p6)+SUM4(p7)+
                SUM4(p8)+SUM4(p9)+SUM4(p10)+SUM4(p11)+SUM4(p12)+SUM4(p13)+SUM4(p14)+SUM4(p15);
    float inv_x = 1.f / (sqrtf(ssx) + EPSV);

    const float4* __restrict__ wd4 = (const float4*)(winT + (size_t)dir * HH);
    float4* bo = (float4*)(buf0 + (size_t)r * HH);
    float ssg = 0.f, sgl = 0.f;
#define INIT_SG(JJ, COMP) { \
      const float* rp_ = Wr + (size_t)(h0 * 4 + JJ) * HH; \
      f32x16 wa_, wb_, wc_, wd_; \
      SLOAD32(wa_, wb_, rp_); \
      float acc_ = DOTQ(p0,p1,p2,p3,wa_) + DOTQ(p4,p5,p6,p7,wb_); \
      SLOAD32(wc_, wd_, rp_ + 32); \
      acc_ += DOTQ(p8,p9,p10,p11,wc_) + DOTQ(p12,p13,p14,p15,wd_); \
      u.COMP = fmaxf(fmaf(inv_x, acc_, d4.COMP), 0.f); }
    #pragma unroll 1
    for (int h0 = 0; h0 < 16; ++h0) {
      float4 d4 = wd4[h0];
      float4 u;
      INIT_SG(0, x) INIT_SG(1, y) INIT_SG(2, z) INIT_SG(3, w)
      bo[h0] = u;
      ssg += SUMSQ4(u); sgl += SUM4(u);
    }
    float inv_g = 1.f / (sqrtf(ssg) + EPSV);
    scl0[r] = inv_g;
    a_s = inv_g;
    sg = sgl;
    gate0 = inv_x * sx - inv_g * sgl;
  }

  __syncthreads();   // live-range firewall: x row dies here

  // ---- pass 2: s0 row from L1-hot buf0; logits via Wout rows (SGPR) ----
  const float4* __restrict__ sr4 = (const float4*)(buf0 + (size_t)r * HH);
  float zz[NOB];
  {
    LOADP(sr4);   // s0 raw row in p-regs
    #pragma unroll
    for (int o = 0; o < NOB; ++o) {
      const float* rp_ = Wout + (size_t)o * HH;
      f32x16 wa_, wb_, wc_, wd_;
      SLOAD32(wa_, wb_, rp_);
      float acc_ = DOTQ(p0,p1,p2,p3,wa_) + DOTQ(p4,p5,p6,p7,wb_);
      SLOAD32(wc_, wd_, rp_ + 32);
      acc_ += DOTQ(p8,p9,p10,p11,wc_) + DOTQ(p12,p13,p14,p15,wd_);
      zz[o] = acc_;
    }
  }

  SOFTJP(zz, a_s, ob)

  // ---- phase C: g == raw s0 (iteration-0 identity); wotT rows via SGPR ----
  float4* wo4 = (float4*)(buf1 + (size_t)r * HH);
  float ssu = 0.f, su = 0.f;
#define PC_SG(JJ, COMP) { \
    const float* rp_ = wotT + (size_t)(h0 * 4 + JJ) * NOB; \
    f32x16 wa_, wb_; \
    SLOAD32(wa_, wb_, rp_); \
    float w_ = DOTZZ(wa_, wb_); \
    float g_ = g4.COMP; \
    float sv_ = a_s * g_; \
    float uu_ = fmaf(LR_IT, g_ - sv_ + w_, sv_); \
    u.COMP = uu_; ssu += uu_ * uu_; su += uu_; }
  #pragma unroll 1
  for (int h0 = 0; h0 < 16; ++h0) {
    float4 g4 = sr4[h0];
    float4 u;
    PC_SG(0, x) PC_SG(1, y) PC_SG(2, z) PC_SG(3, w)
    wo4[h0] = u;
  }
  float inv_u = 1.f / (sqrtf(ssu) + EPSV);
  scl1[r] = inv_u;
  float gate1 = a_s * sg - inv_u * su;

  float tot0 = block_reduce_all(gate0, red, t);
  if (t == 0) partials0[blockIdx.x] = tot0;
  float tot1 = block_reduce_all(gate1, red, t);
  if (t == 0) partials1[blockIdx.x] = tot1;
}

// ---- resolve: decide act0/act1 (grid-uniform); expected path writes output ----
__global__ __launch_bounds__(TPB, 2) void resolve_kernel(
    float* __restrict__ buf0, float* __restrict__ buf1,
    float* __restrict__ scl0, float* __restrict__ scl1,
    const float* __restrict__ Wr, const float* __restrict__ Wout,
    const float* __restrict__ Win,
    const int* __restrict__ dirs, const int* __restrict__ obs,
    const float* __restrict__ partials0, float* __restrict__ partials,
    int* __restrict__ actArr, float* __restrict__ out)
{
  __shared__ float wrl[HH * WRS];
  __shared__ float wot[HH * WOS];
  __shared__ float wint[NDIRS * WRS];
  __shared__ float red[4];
  int t = threadIdx.x;

  float t0v = block_reduce_all(partials0[t] + partials0[t + TPB], red, t);
  int act0 = (fabsf(t0v * INV_BH) > TOLV) ? 1 : 0;
  float t1v = block_reduce_all(partials[t] + partials[t + TPB], red, t);
  int act1 = (fabsf(t1v * INV_BH) > TOLV) ? 1 : 0;
  if (blockIdx.x == 0 && t == 0) actArr[1] = act0 && act1;

  int r = blockIdx.x * TPB + t;

  if (!act0) {
    if (t == 0) partials[blockIdx.x] = partials0[blockIdx.x];
    stage_wot(Wout, wot, t, TPB);
    __syncthreads();
    final_write(r, scl0[r], buf0, out, wot);
    return;
  }
  if (!act1) {
    stage_wot(Wout, wot, t, TPB);
    __syncthreads();
    final_write(r, scl1[r], buf1, out, wot);
    return;
  }

  // both active: run iteration 1 fully. S=buf1/scl1, P=buf0 (scl0), W=buf0/scl0.
  stage_wr(Wr, wrl, t, TPB);
  stage_wot(Wout, wot, t, TPB);
  stage_wint(Win, wint, t, TPB);
  __syncthreads();

  float a_s = scl1[r];
  float a_p = scl0[r];
  int ob = obs[r];
  int dir = dirs[r];
  const float4* __restrict__ sr4 = (const float4*)(buf1 + (size_t)r * HH);

  float zz[NOB];
  #pragma unroll
  for (int o = 0; o < NOB; ++o) zz[o] = 0.f;
  float sS = 0.f;
  #pragma unroll 1
  for (int h0 = 0; h0 < 16; ++h0) {
    float4 s4 = sr4[h0];
    sS += SUM4(s4);
    const float* t0 = &wot[(h0 * 4 + 0) * WOS];
    const float* t1 = &wot[(h0 * 4 + 1) * WOS];
    const float* t2 = &wot[(h0 * 4 + 2) * WOS];
    const float* t3 = &wot[(h0 * 4 + 3) * WOS];
    #pragma unroll
    for (int o = 0; o < NOB; ++o)
      zz[o] += s4.x * t0[o] + s4.y * t1[o] + s4.z * t2[o] + s4.w * t3[o];
  }
  SOFTJP(zz, a_s, ob)
  __syncthreads();   // live-range firewall

  const float4* __restrict__ pr4 = (const float4*)(buf0 + (size_t)r * HH);
  LOADP(pr4);
  float4* wo4 = (float4*)(buf0 + (size_t)r * HH);
  float ssu = 0.f, su = 0.f;
#define STEP_C_ONE(JJ, COMP) { \
    const float* wr_ = &wrl[(h0 * 4 + JJ) * WRS]; \
    float g_ = fmaxf(fmaf(a_p, DOT64P(wr_), d4.COMP), 0.f); \
    const float* wt_ = &wot[(h0 * 4 + JJ) * WOS]; \
    float w_ = 0.f; \
    _Pragma("unroll") \
    for (int o = 0; o < NOB; ++o) w_ += zz[o] * wt_[o]; \
    float sv_ = a_s * s4.COMP; \
    float uu_ = fmaf(LR_IT, g_ - sv_ + w_, sv_); \
    u.COMP = uu_; ssu += uu_ * uu_; su += uu_; }
  #pragma unroll 1
  for (int h0 = 0; h0 < 16; ++h0) {
    float4 s4 = sr4[h0];
    float4 d4 = *(const float4*)&wint[dir * WRS + h0 * 4];
    float4 u;
    STEP_C_ONE(0, x) STEP_C_ONE(1, y) STEP_C_ONE(2, z) STEP_C_ONE(3, w)
    wo4[h0] = u;
  }
  float inv_u = 1.f / (sqrtf(ssu) + EPSV);
  scl0[r] = inv_u;

  float tot2 = block_reduce_all(a_s * sS - inv_u * su, red, t);
  if (t == 0) partials[blockIdx.x] = tot2;
}

// ---- generic step k>=2: gate + (active | first-inactive final | no-op) ----
__global__ __launch_bounds__(TPB, 2) void step_kernel(
    float* __restrict__ buf0, float* __restrict__ buf1,
    float* __restrict__ scl0, float* __restrict__ scl1,
    const float* __restrict__ Wr, const float* __restrict__ Wout,
    const float* __restrict__ Win,
    const int* __restrict__ dirs, const int* __restrict__ obs,
    float* __restrict__ partials, int* __restrict__ actArr,
    float* __restrict__ out, int k)
{
  __shared__ float red[4];
  __shared__ float wrl[HH * WRS];
  __shared__ float wot[HH * WOS];
  __shared__ float wint[NDIRS * WRS];
  int t = threadIdx.x;

  float tot = block_reduce_all(partials[t] + partials[t + TPB], red, t);
  int active = (fabsf(tot * INV_BH) > TOLV) ? 1 : 0;
  if (blockIdx.x == 0 && t == 0) actArr[k] = active;

  int si = k & 1;
  int r = blockIdx.x * TPB + t;

  if (!active) {
    int first_inactive = actArr[k - 1];
    if (!first_inactive) return;
    stage_wot(Wout, wot, t, TPB);
    __syncthreads();
    const float* S   = si ? buf1 : buf0;
    const float* scl = si ? scl1 : scl0;
    final_write(r, scl[r], S, out, wot);
    return;
  }

  const float* S    = si ? buf1 : buf0;
  const float* sclS = si ? scl1 : scl0;
  float* W          = si ? buf0 : buf1;
  float* sclW       = si ? scl0 : scl1;

  stage_wr(Wr, wrl, t, TPB);
  stage_wot(Wout, wot, t, TPB);
  stage_wint(Win, wint, t, TPB);
  __syncthreads();

  float a_s = sclS[r];
  float a_p = sclW[r];
  int ob = obs[r];
  int dir = dirs[r];
  const float4* __restrict__ sr4 = (const float4*)(S + (size_t)r * HH);

  float zz[NOB];
  #pragma unroll
  for (int o = 0; o < NOB; ++o) zz[o] = 0.f;
  float sS = 0.f;
  #pragma unroll 1
  for (int h0 = 0; h0 < 16; ++h0) {
    float4 s4 = sr4[h0];
    sS += SUM4(s4);
    const float* t0 = &wot[(h0 * 4 + 0) * WOS];
    const float* t1 = &wot[(h0 * 4 + 1) * WOS];
    const float* t2 = &wot[(h0 * 4 + 2) * WOS];
    const float* t3 = &wot[(h0 * 4 + 3) * WOS];
    #pragma unroll
    for (int o = 0; o < NOB; ++o)
      zz[o] += s4.x * t0[o] + s4.y * t1[o] + s4.z * t2[o] + s4.w * t3[o];
  }
  SOFTJP(zz, a_s, ob)
  __syncthreads();

  const float4* __restrict__ pr4 = (const float4*)(W + (size_t)r * HH);
  LOADP(pr4);
  float4* wo4 = (float4*)(W + (size_t)r * HH);
  float ssu = 0.f, su = 0.f;
  #pragma unroll 1
  for (int h0 = 0; h0 < 16; ++h0) {
    float4 s4 = sr4[h0];
    float4 d4 = *(const float4*)&wint[dir * WRS + h0 * 4];
    float4 u;
    STEP_C_ONE(0, x) STEP_C_ONE(1, y) STEP_C_ONE(2, z) STEP_C_ONE(3, w)
    wo4[h0] = u;
  }
  float inv_u = 1.f / (sqrtf(ssu) + EPSV);
  sclW[r] = inv_u;

  float tot2 = block_reduce_all(a_s * sS - inv_u * su, red, t);
  if (t == 0) partials[blockIdx.x] = tot2;
}

// ---- tail: only fires when all 10 iterations were active ----
__global__ __launch_bounds__(TPB, 2) void final_kernel(
    const float* __restrict__ buf0, float* __restrict__ out,
    const float* __restrict__ scl0,
    const float* __restrict__ Wout, const int* __restrict__ actArr)
{
  if (actArr[9] == 0) return;
  __shared__ float wot[HH * WOS];
  int t = threadIdx.x;
  stage_wot(Wout, wot, t, TPB);
  __syncthreads();
  int r = blockIdx.x * TPB + t;
  final_write(r, scl0[r], buf0, out, wot);
}

extern "C" void kernel_launch(void* const* d_in, const int* in_sizes, int n_in,
                              void* d_out, int out_size, void* d_ws, size_t ws_size,
                              hipStream_t stream) {
  const int* dirs = (const int*)d_in[0];
  const int* obs = (const int*)d_in[1];
  const float* x = (const float*)d_in[2];
  const float* Wr = (const float*)d_in[3];
  const float* Win = (const float*)d_in[4];
  const float* Wout = (const float*)d_in[5];
  float* out = (float*)d_out;
  float* ws = (float*)d_ws;

  float* buf0 = ws;                              // B*H raw state s0 (then s2,..)
  float* scl0 = ws + (size_t)BB * HH;            // B
  float* scl1 = scl0 + BB;                       // B
  float* partials = scl1 + BB;                   // NBLK (gate for "current" iteration)
  float* partials0 = partials + NBLK;            // NBLK (gate0)
  int* actArr = (int*)(partials0 + NBLK);        // 16 ints
  float* wotT = (float*)(actArr + 16);           // 64*32
  float* winT = wotT + NOB * HH;                 // 8*64
  float* buf1 = out + (size_t)BB * NOB;          // s-slice of d_out: s1 (then s3,..)

  prep_kernel<<<1, TPB, 0, stream>>>(Wout, Win, wotT, winT);
  fused_kernel<<<NBLK, TPB, 0, stream>>>(x, dirs, obs, Wr, Wout, wotT, winT,
                                         buf0, buf1, scl0, scl1, partials0, partials);
  resolve_kernel<<<NBLK, TPB, 0, stream>>>(buf0, buf1, scl0, scl1, Wr, Wout, Win,
                                           dirs, obs, partials0, partials, actArr, out);
  for (int k = 2; k < 10; ++k)
    step_kernel<<<NBLK, TPB, 0, stream>>>(buf0, buf1, scl0, scl1,
                                          Wr, Wout, Win, dirs, obs, partials, actArr, out, k);
  final_kernel<<<NBLK, TPB, 0, stream>>>(buf0, out, scl0, Wout, actArr);
}

// Round 18
// 116.791 us; speedup vs baseline: 5.5363x; 1.6273x over previous
//
#include <hip/hip_runtime.h>
#include <math.h>

#define BB 131072
#define HH 64
#define NOB 32
#define NDIRS 8
#define LR_IT 1e-3f
#define TOLV 1e-3f
#define EPSV 1e-6f
#define NBLK 512
#define NBF  2048      // fused grid (64 rows/block)
#define RPB  64
#define TPB 256
#define WRS 68
#define WOS 36
#define INV_BH (1.0f/8388608.0f)

typedef _Float16 f16x8 __attribute__((ext_vector_type(8)));
typedef float f32x4v __attribute__((ext_vector_type(4)));

// ---------------- legacy helpers (resolve/step/final, proven r11 bodies) --------------
#define D16(pp, Wp, b) ((pp).x*(Wp)[(b)+0] + (pp).y*(Wp)[(b)+1] + (pp).z*(Wp)[(b)+2] + (pp).w*(Wp)[(b)+3])
#define DOT64P(Wp) (D16(p0,Wp,0)+D16(p1,Wp,4)+D16(p2,Wp,8)+D16(p3,Wp,12)+ \
                    D16(p4,Wp,16)+D16(p5,Wp,20)+D16(p6,Wp,24)+D16(p7,Wp,28)+ \
                    D16(p8,Wp,32)+D16(p9,Wp,36)+D16(p10,Wp,40)+D16(p11,Wp,44)+ \
                    D16(p12,Wp,48)+D16(p13,Wp,52)+D16(p14,Wp,56)+D16(p15,Wp,60))
#define LOADP(src) \
  float4 p0=(src)[0], p1=(src)[1], p2=(src)[2], p3=(src)[3], \
         p4=(src)[4], p5=(src)[5], p6=(src)[6], p7=(src)[7], \
         p8=(src)[8], p9=(src)[9], p10=(src)[10], p11=(src)[11], \
         p12=(src)[12], p13=(src)[13], p14=(src)[14], p15=(src)[15];
#define SUMSQ4(pp) ((pp).x*(pp).x + (pp).y*(pp).y + (pp).z*(pp).z + (pp).w*(pp).w)
#define SUM4(pp) ((pp).x + (pp).y + (pp).z + (pp).w)

__device__ __forceinline__ void stage_wr(const float* __restrict__ Wr, float* wrl, int t, int bs) {
  const float4* g = (const float4*)Wr;
  for (int i = t; i < 1024; i += bs) {
    int h = i >> 4, k4 = i & 15;
    *(float4*)&wrl[h * WRS + k4 * 4] = g[i];
  }
}
__device__ __forceinline__ void stage_wot(const float* __restrict__ Wout, float* wot, int t, int bs) {
  for (int i = t; i < NOB * HH; i += bs) {
    int o = i >> 6, h = i & 63;
    wot[h * WOS + o] = Wout[i];
  }
}
__device__ __forceinline__ void stage_wint(const float* __restrict__ Win, float* wint, int t, int bs) {
  for (int i = t; i < HH * NDIRS; i += bs) {
    int h = i >> 3, d = i & 7;
    wint[d * WRS + h] = Win[i];
  }
}

__device__ __forceinline__ float block_reduce_all(float v, float* red, int t) {
  #pragma unroll
  for (int off = 32; off > 0; off >>= 1) v += __shfl_down(v, off);
  __syncthreads();
  if ((t & 63) == 0) red[t >> 6] = v;
  __syncthreads();
  return red[0] + red[1] + red[2] + red[3];
}

// reduce the NBF-entry gate array with a 256-thread block
__device__ __forceinline__ float gate_reduce_nbf(const float* __restrict__ p, float* red, int t) {
  float v = 0.f;
  #pragma unroll
  for (int j = 0; j < NBF / TPB; ++j) v += p[t + TPB * j];
  return block_reduce_all(v, red, t);
}

#define SOFTJP(zzp, a_sv, obv) { \
  float m_ = -1e30f; \
  _Pragma("unroll") for (int o_=0;o_<NOB;++o_) m_ = fmaxf(m_, (zzp)[o_]); \
  float se_ = 0.f; \
  _Pragma("unroll") for (int o_=0;o_<NOB;++o_){ (zzp)[o_]=__expf((a_sv)*((zzp)[o_]-m_)); se_+=(zzp)[o_];} \
  float rse_ = 1.f/se_; float fob_=0.f, sf2_=0.f; \
  _Pragma("unroll") for (int o_=0;o_<NOB;++o_){ float f_=(zzp)[o_]*rse_; (zzp)[o_]=f_; sf2_+=f_*f_; fob_ += (o_==(obv))?f_:0.f;} \
  float fe_ = fob_ - sf2_; \
  _Pragma("unroll") for (int o_=0;o_<NOB;++o_){ float ep_=((o_==(obv))?1.f:0.f)-(zzp)[o_]; (zzp)[o_]=(zzp)[o_]*(ep_-fe_);} }

__device__ __forceinline__ void final_write(
    int r, float a_s, const float* __restrict__ S, float* __restrict__ out,
    const float* wot) {
  const float4* __restrict__ sr4 = (const float4*)(S + (size_t)r * HH);
  float zz[NOB];
  #pragma unroll
  for (int o = 0; o < NOB; ++o) zz[o] = 0.f;
  #pragma unroll 1
  for (int h0 = 0; h0 < 16; ++h0) {
    float4 s4 = sr4[h0];
    const float* t0 = &wot[(h0 * 4 + 0) * WOS];
    const float* t1 = &wot[(h0 * 4 + 1) * WOS];
    const float* t2 = &wot[(h0 * 4 + 2) * WOS];
    const float* t3 = &wot[(h0 * 4 + 3) * WOS];
    #pragma unroll
    for (int o = 0; o < NOB; ++o)
      zz[o] += s4.x * t0[o] + s4.y * t1[o] + s4.z * t2[o] + s4.w * t3[o];
  }
  float m = -1e30f;
  #pragma unroll
  for (int o = 0; o < NOB; ++o) m = fmaxf(m, zz[o]);
  float se = 0.f;
  #pragma unroll
  for (int o = 0; o < NOB; ++o) { zz[o] = __expf(a_s * (zz[o] - m)); se += zz[o]; }
  float rse = 1.f / se;

  float4* po = (float4*)(out + (size_t)r * NOB);
  #pragma unroll
  for (int o4 = 0; o4 < 8; ++o4) {
    float4 f;
    f.x = zz[o4 * 4 + 0] * rse; f.y = zz[o4 * 4 + 1] * rse;
    f.z = zz[o4 * 4 + 2] * rse; f.w = zz[o4 * 4 + 3] * rse;
    po[o4] = f;
  }
  float4* so = (float4*)(out + (size_t)BB * NOB + (size_t)r * HH);
  #pragma unroll 1
  for (int h0 = 0; h0 < 16; ++h0) {
    float4 s4 = sr4[h0];
    s4.x *= a_s; s4.y *= a_s; s4.z *= a_s; s4.w *= a_s;
    so[h0] = s4;
  }
}

// ---- prep: wotT[h][o] = Wout[o][h]; winT[d][h] = Win[h][d] ----
__global__ __launch_bounds__(TPB) void prep_kernel(
    const float* __restrict__ Wout, const float* __restrict__ Win,
    float* __restrict__ wotT, float* __restrict__ winT)
{
  int t = threadIdx.x;
  for (int i = t; i < NOB * HH; i += TPB) { int h = i >> 5, o = i & 31; wotT[i] = Wout[o * HH + h]; }
  for (int i = t; i < NDIRS * HH; i += TPB) { int d = i >> 6, h = i & 63; winT[i] = Win[h * NDIRS + d]; }
}

// ---- helper: load 8 consecutive f32 -> f16x8 fragment ----
__device__ __forceinline__ f16x8 ldb8(const float* __restrict__ p) {
  float4 a = *(const float4*)p;
  float4 b = *(const float4*)(p + 4);
  f16x8 r;
  r[0]=(_Float16)a.x; r[1]=(_Float16)a.y; r[2]=(_Float16)a.z; r[3]=(_Float16)a.w;
  r[4]=(_Float16)b.x; r[5]=(_Float16)b.y; r[6]=(_Float16)b.z; r[7]=(_Float16)b.w;
  return r;
}

#define MFMA16(a, b, c) __builtin_amdgcn_mfma_f32_16x16x32_f16((a), (b), (c), 0, 0, 0)

// ---- fused (MFMA): init + iteration-0 candidate. 1 wave = 16 rows, 4 waves/block. ----
__global__ __launch_bounds__(TPB, 2) void fused_kernel(
    const float* __restrict__ x, const int* __restrict__ dirs,
    const int* __restrict__ obs,
    const float* __restrict__ Wr, const float* __restrict__ Wout,
    const float* __restrict__ wotT, const float* __restrict__ winT,
    float* __restrict__ buf0, float* __restrict__ buf1,
    float* __restrict__ scl0, float* __restrict__ scl1,
    float* __restrict__ partials0, float* __restrict__ partials1)
{
  __shared__ float s0sh[4 * 16 * 68];
  __shared__ float jpsh[4 * 16 * 36];
  __shared__ float red0[4], red1[4];
  int t = threadIdx.x;
  int w = t >> 6, l = t & 63;
  int l15 = l & 15, lg = l >> 4;
  int rbase = blockIdx.x * RPB + w * 16;
  float* s0l = &s0sh[w * 16 * 68];
  float* jpl = &jpsh[w * 16 * 36];

  // ---- B-fragments (held in VGPRs for the whole kernel) ----
  // GEMM1 (x@WrT): B[k][j=h] = Wr[16T+j][k]
  f16x8 bWr[4][2];
  #pragma unroll
  for (int T = 0; T < 4; ++T)
    #pragma unroll
    for (int c = 0; c < 2; ++c)
      bWr[T][c] = ldb8(Wr + (size_t)(16*T + l15) * HH + 32*c + lg*8);
  // GEMM2 (s0@WoutT): B[k=h][j=o] = Wout[16T+j][k]
  f16x8 bWo[2][2];
  #pragma unroll
  for (int T = 0; T < 2; ++T)
    #pragma unroll
    for (int c = 0; c < 2; ++c)
      bWo[T][c] = ldb8(Wout + (size_t)(16*T + l15) * HH + 32*c + lg*8);
  // GEMM3 (jp@Wout): B[k=o][j=h] = Wout[k][16T+j] = wotT[16T+j][k]
  f16x8 bWt[4];
  #pragma unroll
  for (int T = 0; T < 4; ++T)
    bWt[T] = ldb8(wotT + (size_t)(16*T + l15) * NOB + lg*8);

  // ---- phase 1: x A-frags (lane: row=l15, k=lg*8..+8 per chunk) + row stats ----
  const float4* __restrict__ xr = (const float4*)(x + (size_t)(rbase + l15) * HH);
  float4 xa0 = xr[lg*2],     xa1 = xr[lg*2 + 1];       // k in [lg*8, lg*8+8)
  float4 xb0 = xr[8 + lg*2], xb1 = xr[8 + lg*2 + 1];   // k in [32+lg*8, ...)
  f16x8 ax0 = ldb8((const float*)&xa0 - 0);            // avoid reload: build directly
  // build frags from the already-loaded registers:
  {
    f16x8 r;
    r[0]=(_Float16)xa0.x; r[1]=(_Float16)xa0.y; r[2]=(_Float16)xa0.z; r[3]=(_Float16)xa0.w;
    r[4]=(_Float16)xa1.x; r[5]=(_Float16)xa1.y; r[6]=(_Float16)xa1.z; r[7]=(_Float16)xa1.w;
    ax0 = r;
  }
  f16x8 ax1;
  {
    f16x8 r;
    r[0]=(_Float16)xb0.x; r[1]=(_Float16)xb0.y; r[2]=(_Float16)xb0.z; r[3]=(_Float16)xb0.w;
    r[4]=(_Float16)xb1.x; r[5]=(_Float16)xb1.y; r[6]=(_Float16)xb1.z; r[7]=(_Float16)xb1.w;
    ax1 = r;
  }
  float ssx = SUMSQ4(xa0)+SUMSQ4(xa1)+SUMSQ4(xb0)+SUMSQ4(xb1);
  float sx  = SUM4(xa0)+SUM4(xa1)+SUM4(xb0)+SUM4(xb1);
  ssx += __shfl_xor(ssx, 16); ssx += __shfl_xor(ssx, 32);
  sx  += __shfl_xor(sx, 16);  sx  += __shfl_xor(sx, 32);
  float inv_x = 1.f / (sqrtf(ssx) + EPSV);   // row l15

  // ---- GEMM1: acc[T] = x @ Wr^T tile ----
  f32x4v acc[4];
  #pragma unroll
  for (int T = 0; T < 4; ++T) {
    f32x4v c = {0.f, 0.f, 0.f, 0.f};
    c = MFMA16(ax0, bWr[T][0], c);
    c = MFMA16(ax1, bWr[T][1], c);
    acc[T] = c;
  }

  // ---- phase 3: s0 = relu(inv_x*acc + drive); D-layout rows r=4*lg+reg, col h=16T+l15 ----
  float invxr[4], sxr[4];
  int dirr[4], obr[4];
  #pragma unroll
  for (int reg = 0; reg < 4; ++reg) {
    invxr[reg] = __shfl(inv_x, 4*lg + reg);
    sxr[reg]   = __shfl(sx,    4*lg + reg);
    dirr[reg]  = dirs[rbase + 4*lg + reg];
    obr[reg]   = obs [rbase + 4*lg + reg];
  }
  float s0v[4][4];    // [T][reg]
  float ssg[4] = {0.f,0.f,0.f,0.f}, sgv[4] = {0.f,0.f,0.f,0.f};
  #pragma unroll
  for (int T = 0; T < 4; ++T)
    #pragma unroll
    for (int reg = 0; reg < 4; ++reg) {
      float drive = winT[dirr[reg] * HH + 16*T + l15];
      float v = fmaxf(fmaf(invxr[reg], acc[T][reg], drive), 0.f);
      s0v[T][reg] = v;
      ssg[reg] += v * v; sgv[reg] += v;
    }
  #pragma unroll
  for (int reg = 0; reg < 4; ++reg) {
    #pragma unroll
    for (int m = 1; m < 16; m <<= 1) {
      ssg[reg] += __shfl_xor(ssg[reg], m);
      sgv[reg] += __shfl_xor(sgv[reg], m);
    }
  }
  float invg[4];
  #pragma unroll
  for (int reg = 0; reg < 4; ++reg) invg[reg] = 1.f / (sqrtf(ssg[reg]) + EPSV);
  if (l15 == 0) {
    #pragma unroll
    for (int reg = 0; reg < 4; ++reg) scl0[rbase + 4*lg + reg] = invg[reg];
  }
  float g0 = 0.f;
  if (l15 == 0) {
    #pragma unroll
    for (int reg = 0; reg < 4; ++reg)
      g0 += invxr[reg] * sxr[reg] - invg[reg] * sgv[reg];
  }

  // s0 -> LDS (wave-private tile [16][68]) ; then coalesced global write of buf0
  #pragma unroll
  for (int T = 0; T < 4; ++T)
    #pragma unroll
    for (int reg = 0; reg < 4; ++reg)
      s0l[(4*lg + reg) * 68 + 16*T + l15] = s0v[T][reg];
  {
    int rr = l >> 2, cc = (l & 3) * 16;
    const float4* srcl = (const float4*)(s0l + rr * 68 + cc);
    float4* dst = (float4*)(buf0 + (size_t)(rbase + rr) * HH + cc);
    dst[0] = srcl[0]; dst[1] = srcl[1]; dst[2] = srcl[2]; dst[3] = srcl[3];
  }

  // ---- GEMM2: logits = s0 @ WoutT ; A-frags from LDS (row=l15, k=lg*8 / +32) ----
  f16x8 as0, as1;
  {
    const float* pr = s0l + l15 * 68 + lg * 8;
    as0 = ldb8(pr);
    as1 = ldb8(pr + 32);
  }
  f32x4v lac[2];
  #pragma unroll
  for (int T = 0; T < 2; ++T) {
    f32x4v c = {0.f, 0.f, 0.f, 0.f};
    c = MFMA16(as0, bWo[T][0], c);
    c = MFMA16(as1, bWo[T][1], c);
    lac[T] = c;
  }

  // ---- phase 5: softmax + jacobian per row (row r=4*lg+reg; lane holds o=l15, 16+l15) ----
  float jp0[4], jp1[4];
  #pragma unroll
  for (int reg = 0; reg < 4; ++reg) {
    float z0 = lac[0][reg], z1 = lac[1][reg];
    float m = fmaxf(z0, z1);
    #pragma unroll
    for (int mm = 1; mm < 16; mm <<= 1) m = fmaxf(m, __shfl_xor(m, mm));
    float e0 = __expf(invg[reg] * (z0 - m));
    float e1 = __expf(invg[reg] * (z1 - m));
    float se = e0 + e1;
    #pragma unroll
    for (int mm = 1; mm < 16; mm <<= 1) se += __shfl_xor(se, mm);
    float rse = 1.f / se;
    float f0 = e0 * rse, f1 = e1 * rse;
    int ob = obr[reg];
    float on0 = (l15 == ob) ? 1.f : 0.f;
    float on1 = (16 + l15 == ob) ? 1.f : 0.f;
    float fob = on0 * f0 + on1 * f1;
    float sf2 = f0 * f0 + f1 * f1;
    #pragma unroll
    for (int mm = 1; mm < 16; mm <<= 1) {
      fob += __shfl_xor(fob, mm);
      sf2 += __shfl_xor(sf2, mm);
    }
    float fe = fob - sf2;
    jp0[reg] = f0 * (on0 - f0 - fe);
    jp1[reg] = f1 * (on1 - f1 - fe);
  }

  // jp -> LDS [16][36], then A-frag (row=l15, k=o=lg*8..+8)
  #pragma unroll
  for (int reg = 0; reg < 4; ++reg) {
    jpl[(4*lg + reg) * 36 + l15]      = jp0[reg];
    jpl[(4*lg + reg) * 36 + 16 + l15] = jp1[reg];
  }
  f16x8 ajp;
  {
    const float* pr = jpl + l15 * 36 + lg * 8;
    ajp = ldb8(pr);
  }

  // ---- GEMM3: pv = jp @ Wout ----
  f32x4v pv[4];
  #pragma unroll
  for (int T = 0; T < 4; ++T) {
    f32x4v c = {0.f, 0.f, 0.f, 0.f};
    pv[T] = MFMA16(ajp, bWt[T], c);
  }

  // ---- phase 8: s1 = a_s*s0 + LR*(s0 - a_s*s0 + pv); stats; writes ----
  float ssu[4] = {0.f,0.f,0.f,0.f}, suv[4] = {0.f,0.f,0.f,0.f};
  #pragma unroll
  for (int T = 0; T < 4; ++T)
    #pragma unroll
    for (int reg = 0; reg < 4; ++reg) {
      float s0_ = s0v[T][reg];
      float sv = invg[reg] * s0_;
      float u = fmaf(LR_IT, s0_ - sv + pv[T][reg], sv);
      s0v[T][reg] = u;            // reuse storage for s1
      ssu[reg] += u * u; suv[reg] += u;
    }
  #pragma unroll
  for (int reg = 0; reg < 4; ++reg) {
    #pragma unroll
    for (int m = 1; m < 16; m <<= 1) {
      ssu[reg] += __shfl_xor(ssu[reg], m);
      suv[reg] += __shfl_xor(suv[reg], m);
    }
  }
  float invu[4];
  #pragma unroll
  for (int reg = 0; reg < 4; ++reg) invu[reg] = 1.f / (sqrtf(ssu[reg]) + EPSV);
  if (l15 == 0) {
    #pragma unroll
    for (int reg = 0; reg < 4; ++reg) scl1[rbase + 4*lg + reg] = invu[reg];
  }
  float g1 = 0.f;
  if (l15 == 0) {
    #pragma unroll
    for (int reg = 0; reg < 4; ++reg)
      g1 += invg[reg] * sgv[reg] - invu[reg] * suv[reg];
  }

  // s1 -> LDS (reuse s0l) -> coalesced buf1 write
  #pragma unroll
  for (int T = 0; T < 4; ++T)
    #pragma unroll
    for (int reg = 0; reg < 4; ++reg)
      s0l[(4*lg + reg) * 68 + 16*T + l15] = s0v[T][reg];
  {
    int rr = l >> 2, cc = (l & 3) * 16;
    const float4* srcl = (const float4*)(s0l + rr * 68 + cc);
    float4* dst = (float4*)(buf1 + (size_t)(rbase + rr) * HH + cc);
    dst[0] = srcl[0]; dst[1] = srcl[1]; dst[2] = srcl[2]; dst[3] = srcl[3];
  }

  // ---- gates: wave totals -> block totals ----
  g0 += __shfl_xor(g0, 16); g0 += __shfl_xor(g0, 32);
  g1 += __shfl_xor(g1, 16); g1 += __shfl_xor(g1, 32);
  if (l == 0) { red0[w] = g0; red1[w] = g1; }
  __syncthreads();
  if (t == 0) {
    partials0[blockIdx.x] = red0[0] + red0[1] + red0[2] + red0[3];
    partials1[blockIdx.x] = red1[0] + red1[1] + red1[2] + red1[3];
  }
}

// ---- resolve: decide act0/act1 (grid-uniform); expected path writes output ----
__global__ __launch_bounds__(TPB, 2) void resolve_kernel(
    float* __restrict__ buf0, float* __restrict__ buf1,
    float* __restrict__ scl0, float* __restrict__ scl1,
    const float* __restrict__ Wr, const float* __restrict__ Wout,
    const float* __restrict__ Win,
    const int* __restrict__ dirs, const int* __restrict__ obs,
    const float* __restrict__ partials0, float* __restrict__ partials,
    int* __restrict__ actArr, float* __restrict__ out)
{
  __shared__ float wrl[HH * WRS];
  __shared__ float wot[HH * WOS];
  __shared__ float wint[NDIRS * WRS];
  __shared__ float red[4];
  int t = threadIdx.x;

  float t0v = gate_reduce_nbf(partials0, red, t);
  int act0 = (fabsf(t0v * INV_BH) > TOLV) ? 1 : 0;
  float t1v = gate_reduce_nbf(partials, red, t);
  int act1 = (fabsf(t1v * INV_BH) > TOLV) ? 1 : 0;
  if (blockIdx.x == 0 && t == 0) actArr[1] = act0 && act1;

  int r = blockIdx.x * TPB + t;

  if (!act0) {
    // iteration 0 inactive: final = s0; keep sticky invariant on full NBF array
    if (t < 4) partials[blockIdx.x * 4 + t] = partials0[blockIdx.x * 4 + t];
    stage_wot(Wout, wot, t, TPB);
    __syncthreads();
    final_write(r, scl0[r], buf0, out, wot);
    return;
  }
  if (!act1) {
    stage_wot(Wout, wot, t, TPB);
    __syncthreads();
    final_write(r, scl1[r], buf1, out, wot);
    return;
  }

  // both active: run iteration 1 fully. S=buf1/scl1, P=buf0 (scl0), W=buf0/scl0.
  stage_wr(Wr, wrl, t, TPB);
  stage_wot(Wout, wot, t, TPB);
  stage_wint(Win, wint, t, TPB);
  __syncthreads();

  float a_s = scl1[r];
  float a_p = scl0[r];
  int ob = obs[r];
  int dir = dirs[r];
  const float4* __restrict__ sr4 = (const float4*)(buf1 + (size_t)r * HH);

  float zz[NOB];
  #pragma unroll
  for (int o = 0; o < NOB; ++o) zz[o] = 0.f;
  float sS = 0.f;
  #pragma unroll 1
  for (int h0 = 0; h0 < 16; ++h0) {
    float4 s4 = sr4[h0];
    sS += SUM4(s4);
    const float* t0 = &wot[(h0 * 4 + 0) * WOS];
    const float* t1 = &wot[(h0 * 4 + 1) * WOS];
    const float* t2 = &wot[(h0 * 4 + 2) * WOS];
    const float* t3 = &wot[(h0 * 4 + 3) * WOS];
    #pragma unroll
    for (int o = 0; o < NOB; ++o)
      zz[o] += s4.x * t0[o] + s4.y * t1[o] + s4.z * t2[o] + s4.w * t3[o];
  }
  SOFTJP(zz, a_s, ob)
  __syncthreads();   // live-range firewall

  const float4* __restrict__ pr4 = (const float4*)(buf0 + (size_t)r * HH);
  LOADP(pr4);
  float4* wo4 = (float4*)(buf0 + (size_t)r * HH);
  float ssu = 0.f, su = 0.f;
#define STEP_C_ONE(JJ, COMP) { \
    const float* wr_ = &wrl[(h0 * 4 + JJ) * WRS]; \
    float g_ = fmaxf(fmaf(a_p, DOT64P(wr_), d4.COMP), 0.f); \
    const float* wt_ = &wot[(h0 * 4 + JJ) * WOS]; \
    float w_ = 0.f; \
    _Pragma("unroll") \
    for (int o = 0; o < NOB; ++o) w_ += zz[o] * wt_[o]; \
    float sv_ = a_s * s4.COMP; \
    float uu_ = fmaf(LR_IT, g_ - sv_ + w_, sv_); \
    u.COMP = uu_; ssu += uu_ * uu_; su += uu_; }
  #pragma unroll 1
  for (int h0 = 0; h0 < 16; ++h0) {
    float4 s4 = sr4[h0];
    float4 d4 = *(const float4*)&wint[dir * WRS + h0 * 4];
    float4 u;
    STEP_C_ONE(0, x) STEP_C_ONE(1, y) STEP_C_ONE(2, z) STEP_C_ONE(3, w)
    wo4[h0] = u;
  }
  float inv_u = 1.f / (sqrtf(ssu) + EPSV);
  scl0[r] = inv_u;

  float tot2 = block_reduce_all(a_s * sS - inv_u * su, red, t);
  if (t == 0) partials[blockIdx.x] = tot2;
  if (t == 1) partials[blockIdx.x + NBLK] = 0.f;
  if (t == 2) partials[blockIdx.x + 2 * NBLK] = 0.f;
  if (t == 3) partials[blockIdx.x + 3 * NBLK] = 0.f;
}

// ---- generic step k>=2: gate + (active | first-inactive final | no-op) ----
__global__ __launch_bounds__(TPB, 2) void step_kernel(
    float* __restrict__ buf0, float* __restrict__ buf1,
    float* __restrict__ scl0, float* __restrict__ scl1,
    const float* __restrict__ Wr, const float* __restrict__ Wout,
    const float* __restrict__ Win,
    const int* __restrict__ dirs, const int* __restrict__ obs,
    float* __restrict__ partials, int* __restrict__ actArr,
    float* __restrict__ out, int k)
{
  __shared__ float red[4];
  __shared__ float wrl[HH * WRS];
  __shared__ float wot[HH * WOS];
  __shared__ float wint[NDIRS * WRS];
  int t = threadIdx.x;

  float tot = gate_reduce_nbf(partials, red, t);
  int active = (fabsf(tot * INV_BH) > TOLV) ? 1 : 0;
  if (blockIdx.x == 0 && t == 0) actArr[k] = active;

  int si = k & 1;
  int r = blockIdx.x * TPB + t;

  if (!active) {
    int first_inactive = actArr[k - 1];
    if (!first_inactive) return;
    stage_wot(Wout, wot, t, TPB);
    __syncthreads();
    const float* S   = si ? buf1 : buf0;
    const float* scl = si ? scl1 : scl0;
    final_write(r, scl[r], S, out, wot);
    return;
  }

  const float* S    = si ? buf1 : buf0;
  const float* sclS = si ? scl1 : scl0;
  float* W          = si ? buf0 : buf1;
  float* sclW       = si ? scl0 : scl1;

  stage_wr(Wr, wrl, t, TPB);
  stage_wot(Wout, wot, t, TPB);
  stage_wint(Win, wint, t, TPB);
  __syncthreads();

  float a_s = sclS[r];
  float a_p = sclW[r];
  int ob = obs[r];
  int dir = dirs[r];
  const float4* __restrict__ sr4 = (const float4*)(S + (size_t)r * HH);

  float zz[NOB];
  #pragma unroll
  for (int o = 0; o < NOB; ++o) zz[o] = 0.f;
  float sS = 0.f;
  #pragma unroll 1
  for (int h0 = 0; h0 < 16; ++h0) {
    float4 s4 = sr4[h0];
    sS += SUM4(s4);
    const float* t0 = &wot[(h0 * 4 + 0) * WOS];
    const float* t1 = &wot[(h0 * 4 + 1) * WOS];
    const float* t2 = &wot[(h0 * 4 + 2) * WOS];
    const float* t3 = &wot[(h0 * 4 + 3) * WOS];
    #pragma unroll
    for (int o = 0; o < NOB; ++o)
      zz[o] += s4.x * t0[o] + s4.y * t1[o] + s4.z * t2[o] + s4.w * t3[o];
  }
  SOFTJP(zz, a_s, ob)
  __syncthreads();

  const float4* __restrict__ pr4 = (const float4*)(W + (size_t)r * HH);
  LOADP(pr4);
  float4* wo4 = (float4*)(W + (size_t)r * HH);
  float ssu = 0.f, su = 0.f;
  #pragma unroll 1
  for (int h0 = 0; h0 < 16; ++h0) {
    float4 s4 = sr4[h0];
    float4 d4 = *(const float4*)&wint[dir * WRS + h0 * 4];
    float4 u;
    STEP_C_ONE(0, x) STEP_C_ONE(1, y) STEP_C_ONE(2, z) STEP_C_ONE(3, w)
    wo4[h0] = u;
  }
  float inv_u = 1.f / (sqrtf(ssu) + EPSV);
  sclW[r] = inv_u;

  float tot2 = block_reduce_all(a_s * sS - inv_u * su, red, t);
  if (t == 0) partials[blockIdx.x] = tot2;
  if (t == 1) partials[blockIdx.x + NBLK] = 0.f;
  if (t == 2) partials[blockIdx.x + 2 * NBLK] = 0.f;
  if (t == 3) partials[blockIdx.x + 3 * NBLK] = 0.f;
}

// ---- tail: only fires when all 10 iterations were active ----
__global__ __launch_bounds__(TPB, 2) void final_kernel(
    const float* __restrict__ buf0, float* __restrict__ out,
    const float* __restrict__ scl0,
    const float* __restrict__ Wout, const int* __restrict__ actArr)
{
  if (actArr[9] == 0) return;
  __shared__ float wot[HH * WOS];
  int t = threadIdx.x;
  stage_wot(Wout, wot, t, TPB);
  __syncthreads();
  int r = blockIdx.x * TPB + t;
  final_write(r, scl0[r], buf0, out, wot);
}

extern "C" void kernel_launch(void* const* d_in, const int* in_sizes, int n_in,
                              void* d_out, int out_size, void* d_ws, size_t ws_size,
                              hipStream_t stream) {
  const int* dirs = (const int*)d_in[0];
  const int* obs = (const int*)d_in[1];
  const float* x = (const float*)d_in[2];
  const float* Wr = (const float*)d_in[3];
  const float* Win = (const float*)d_in[4];
  const float* Wout = (const float*)d_in[5];
  float* out = (float*)d_out;
  float* ws = (float*)d_ws;

  float* buf0 = ws;                              // B*H raw state s0 (then s2,..)
  float* scl0 = ws + (size_t)BB * HH;            // B
  float* scl1 = scl0 + BB;                       // B
  float* partials = scl1 + BB;                   // NBF (gate for "current" iteration)
  float* partials0 = partials + NBF;             // NBF (gate0)
  int* actArr = (int*)(partials0 + NBF);         // 16 ints
  float* wotT = (float*)(actArr + 16);           // 64*32
  float* winT = wotT + NOB * HH;                 // 8*64
  float* buf1 = out + (size_t)BB * NOB;          // s-slice of d_out: s1 (then s3,..)

  prep_kernel<<<1, TPB, 0, stream>>>(Wout, Win, wotT, winT);
  fused_kernel<<<NBF, TPB, 0, stream>>>(x, dirs, obs, Wr, Wout, wotT, winT,
                                        buf0, buf1, scl0, scl1, partials0, partials);
  resolve_kernel<<<NBLK, TPB, 0, stream>>>(buf0, buf1, scl0, scl1, Wr, Wout, Win,
                                           dirs, obs, partials0, partials, actArr, out);
  for (int k = 2; k < 10; ++k)
    step_kernel<<<NBLK, TPB, 0, stream>>>(buf0, buf1, scl0, scl1,
                                          Wr, Wout, Win, dirs, obs, partials, actArr, out, k);
  final_kernel<<<NBLK, TPB, 0, stream>>>(buf0, out, scl0, Wout, actArr);
}

// Round 19
// 82.536 us; speedup vs baseline: 7.8341x; 1.4150x over previous
//
#include <hip/hip_runtime.h>
#include <math.h>

#define BB 131072
#define HH 64
#define NOB 32
#define NDIRS 8
#define LR_IT 1e-3f
#define TOLV 1e-3f
#define EPSV 1e-6f
#define NBLK 512
#define NBF  2048      // fused grid (64 rows/block)
#define RPB  64
#define TPB 256
#define WRS 68
#define WOS 36
#define INV_BH (1.0f/8388608.0f)

typedef _Float16 f16x8 __attribute__((ext_vector_type(8)));
typedef float f32x4v __attribute__((ext_vector_type(4)));

// ---------------- legacy helpers (resolve/step/final, proven r11 bodies) --------------
#define D16(pp, Wp, b) ((pp).x*(Wp)[(b)+0] + (pp).y*(Wp)[(b)+1] + (pp).z*(Wp)[(b)+2] + (pp).w*(Wp)[(b)+3])
#define DOT64P(Wp) (D16(p0,Wp,0)+D16(p1,Wp,4)+D16(p2,Wp,8)+D16(p3,Wp,12)+ \
                    D16(p4,Wp,16)+D16(p5,Wp,20)+D16(p6,Wp,24)+D16(p7,Wp,28)+ \
                    D16(p8,Wp,32)+D16(p9,Wp,36)+D16(p10,Wp,40)+D16(p11,Wp,44)+ \
                    D16(p12,Wp,48)+D16(p13,Wp,52)+D16(p14,Wp,56)+D16(p15,Wp,60))
#define LOADP(src) \
  float4 p0=(src)[0], p1=(src)[1], p2=(src)[2], p3=(src)[3], \
         p4=(src)[4], p5=(src)[5], p6=(src)[6], p7=(src)[7], \
         p8=(src)[8], p9=(src)[9], p10=(src)[10], p11=(src)[11], \
         p12=(src)[12], p13=(src)[13], p14=(src)[14], p15=(src)[15];
#define SUMSQ4(pp) ((pp).x*(pp).x + (pp).y*(pp).y + (pp).z*(pp).z + (pp).w*(pp).w)
#define SUM4(pp) ((pp).x + (pp).y + (pp).z + (pp).w)

__device__ __forceinline__ void stage_wr(const float* __restrict__ Wr, float* wrl, int t, int bs) {
  const float4* g = (const float4*)Wr;
  for (int i = t; i < 1024; i += bs) {
    int h = i >> 4, k4 = i & 15;
    *(float4*)&wrl[h * WRS + k4 * 4] = g[i];
  }
}
__device__ __forceinline__ void stage_wot(const float* __restrict__ Wout, float* wot, int t, int bs) {
  for (int i = t; i < NOB * HH; i += bs) {
    int o = i >> 6, h = i & 63;
    wot[h * WOS + o] = Wout[i];
  }
}
__device__ __forceinline__ void stage_wint(const float* __restrict__ Win, float* wint, int t, int bs) {
  for (int i = t; i < HH * NDIRS; i += bs) {
    int h = i >> 3, d = i & 7;
    wint[d * WRS + h] = Win[i];
  }
}

__device__ __forceinline__ float block_reduce_all(float v, float* red, int t) {
  #pragma unroll
  for (int off = 32; off > 0; off >>= 1) v += __shfl_down(v, off);
  __syncthreads();
  if ((t & 63) == 0) red[t >> 6] = v;
  __syncthreads();
  return red[0] + red[1] + red[2] + red[3];
}

// reduce the NBF-entry gate array with a 256-thread block
__device__ __forceinline__ float gate_reduce_nbf(const float* __restrict__ p, float* red, int t) {
  float v = 0.f;
  #pragma unroll
  for (int j = 0; j < NBF / TPB; ++j) v += p[t + TPB * j];
  return block_reduce_all(v, red, t);
}

#define SOFTJP(zzp, a_sv, obv) { \
  float m_ = -1e30f; \
  _Pragma("unroll") for (int o_=0;o_<NOB;++o_) m_ = fmaxf(m_, (zzp)[o_]); \
  float se_ = 0.f; \
  _Pragma("unroll") for (int o_=0;o_<NOB;++o_){ (zzp)[o_]=__expf((a_sv)*((zzp)[o_]-m_)); se_+=(zzp)[o_];} \
  float rse_ = 1.f/se_; float fob_=0.f, sf2_=0.f; \
  _Pragma("unroll") for (int o_=0;o_<NOB;++o_){ float f_=(zzp)[o_]*rse_; (zzp)[o_]=f_; sf2_+=f_*f_; fob_ += (o_==(obv))?f_:0.f;} \
  float fe_ = fob_ - sf2_; \
  _Pragma("unroll") for (int o_=0;o_<NOB;++o_){ float ep_=((o_==(obv))?1.f:0.f)-(zzp)[o_]; (zzp)[o_]=(zzp)[o_]*(ep_-fe_);} }

__device__ __forceinline__ void final_write(
    int r, float a_s, const float* __restrict__ S, float* __restrict__ out,
    const float* wot) {
  const float4* __restrict__ sr4 = (const float4*)(S + (size_t)r * HH);
  float zz[NOB];
  #pragma unroll
  for (int o = 0; o < NOB; ++o) zz[o] = 0.f;
  #pragma unroll 1
  for (int h0 = 0; h0 < 16; ++h0) {
    float4 s4 = sr4[h0];
    const float* t0 = &wot[(h0 * 4 + 0) * WOS];
    const float* t1 = &wot[(h0 * 4 + 1) * WOS];
    const float* t2 = &wot[(h0 * 4 + 2) * WOS];
    const float* t3 = &wot[(h0 * 4 + 3) * WOS];
    #pragma unroll
    for (int o = 0; o < NOB; ++o)
      zz[o] += s4.x * t0[o] + s4.y * t1[o] + s4.z * t2[o] + s4.w * t3[o];
  }
  float m = -1e30f;
  #pragma unroll
  for (int o = 0; o < NOB; ++o) m = fmaxf(m, zz[o]);
  float se = 0.f;
  #pragma unroll
  for (int o = 0; o < NOB; ++o) { zz[o] = __expf(a_s * (zz[o] - m)); se += zz[o]; }
  float rse = 1.f / se;

  float4* po = (float4*)(out + (size_t)r * NOB);
  #pragma unroll
  for (int o4 = 0; o4 < 8; ++o4) {
    float4 f;
    f.x = zz[o4 * 4 + 0] * rse; f.y = zz[o4 * 4 + 1] * rse;
    f.z = zz[o4 * 4 + 2] * rse; f.w = zz[o4 * 4 + 3] * rse;
    po[o4] = f;
  }
  float4* so = (float4*)(out + (size_t)BB * NOB + (size_t)r * HH);
  #pragma unroll 1
  for (int h0 = 0; h0 < 16; ++h0) {
    float4 s4 = sr4[h0];
    s4.x *= a_s; s4.y *= a_s; s4.z *= a_s; s4.w *= a_s;
    so[h0] = s4;
  }
}

// ---- prep: wotT[h][o] = Wout[o][h]; winT[d][h] = Win[h][d] ----
__global__ __launch_bounds__(TPB) void prep_kernel(
    const float* __restrict__ Wout, const float* __restrict__ Win,
    float* __restrict__ wotT, float* __restrict__ winT)
{
  int t = threadIdx.x;
  for (int i = t; i < NOB * HH; i += TPB) { int h = i >> 5, o = i & 31; wotT[i] = Wout[o * HH + h]; }
  for (int i = t; i < NDIRS * HH; i += TPB) { int d = i >> 6, h = i & 63; winT[i] = Win[h * NDIRS + d]; }
}

// ---- helper: load 8 consecutive f32 -> f16x8 fragment ----
__device__ __forceinline__ f16x8 ldb8(const float* __restrict__ p) {
  float4 a = *(const float4*)p;
  float4 b = *(const float4*)(p + 4);
  f16x8 r;
  r[0]=(_Float16)a.x; r[1]=(_Float16)a.y; r[2]=(_Float16)a.z; r[3]=(_Float16)a.w;
  r[4]=(_Float16)b.x; r[5]=(_Float16)b.y; r[6]=(_Float16)b.z; r[7]=(_Float16)b.w;
  return r;
}

#define MFMA16(a, b, c) __builtin_amdgcn_mfma_f32_16x16x32_f16((a), (b), (c), 0, 0, 0)

// ---- fused (MFMA): init + iteration-0 candidate + SPECULATIVE final output ----
// 1 wave = 16 rows, 4 waves/block, 4 blocks/CU.
__global__ __launch_bounds__(TPB, 4) void fused_kernel(
    const float* __restrict__ x, const int* __restrict__ dirs,
    const int* __restrict__ obs,
    const float* __restrict__ Wr, const float* __restrict__ Wout,
    const float* __restrict__ wotT, const float* __restrict__ winT,
    float* __restrict__ buf0, float* __restrict__ buf1,
    float* __restrict__ scl0, float* __restrict__ scl1,
    float* __restrict__ partials0, float* __restrict__ partials1,
    float* __restrict__ out)
{
  __shared__ float s0sh[4 * 16 * 68];
  __shared__ float jpsh[4 * 16 * 36];
  __shared__ float red0[4], red1[4];
  int t = threadIdx.x;
  int w = t >> 6, l = t & 63;
  int l15 = l & 15, lg = l >> 4;
  int rbase = blockIdx.x * RPB + w * 16;
  float* s0l = &s0sh[w * 16 * 68];
  float* jpl = &jpsh[w * 16 * 36];

  // ---- B-fragments (VGPR-resident for the whole kernel) ----
  f16x8 bWr[4][2];
  #pragma unroll
  for (int T = 0; T < 4; ++T)
    #pragma unroll
    for (int c = 0; c < 2; ++c)
      bWr[T][c] = ldb8(Wr + (size_t)(16*T + l15) * HH + 32*c + lg*8);
  f16x8 bWo[2][2];
  #pragma unroll
  for (int T = 0; T < 2; ++T)
    #pragma unroll
    for (int c = 0; c < 2; ++c)
      bWo[T][c] = ldb8(Wout + (size_t)(16*T + l15) * HH + 32*c + lg*8);
  f16x8 bWt[4];
  #pragma unroll
  for (int T = 0; T < 4; ++T)
    bWt[T] = ldb8(wotT + (size_t)(16*T + l15) * NOB + lg*8);

  // ---- phase 1: x A-frags + row stats ----
  const float4* __restrict__ xr = (const float4*)(x + (size_t)(rbase + l15) * HH);
  float4 xa0 = xr[lg*2],     xa1 = xr[lg*2 + 1];
  float4 xb0 = xr[8 + lg*2], xb1 = xr[8 + lg*2 + 1];
  f16x8 ax0, ax1;
  {
    f16x8 r;
    r[0]=(_Float16)xa0.x; r[1]=(_Float16)xa0.y; r[2]=(_Float16)xa0.z; r[3]=(_Float16)xa0.w;
    r[4]=(_Float16)xa1.x; r[5]=(_Float16)xa1.y; r[6]=(_Float16)xa1.z; r[7]=(_Float16)xa1.w;
    ax0 = r;
    r[0]=(_Float16)xb0.x; r[1]=(_Float16)xb0.y; r[2]=(_Float16)xb0.z; r[3]=(_Float16)xb0.w;
    r[4]=(_Float16)xb1.x; r[5]=(_Float16)xb1.y; r[6]=(_Float16)xb1.z; r[7]=(_Float16)xb1.w;
    ax1 = r;
  }
  float ssx = SUMSQ4(xa0)+SUMSQ4(xa1)+SUMSQ4(xb0)+SUMSQ4(xb1);
  float sx  = SUM4(xa0)+SUM4(xa1)+SUM4(xb0)+SUM4(xb1);
  ssx += __shfl_xor(ssx, 16); ssx += __shfl_xor(ssx, 32);
  sx  += __shfl_xor(sx, 16);  sx  += __shfl_xor(sx, 32);
  float inv_x = 1.f / (sqrtf(ssx) + EPSV);   // row l15

  // ---- GEMM1: acc[T] = x @ Wr^T tile ----
  f32x4v acc[4];
  #pragma unroll
  for (int T = 0; T < 4; ++T) {
    f32x4v c = {0.f, 0.f, 0.f, 0.f};
    c = MFMA16(ax0, bWr[T][0], c);
    c = MFMA16(ax1, bWr[T][1], c);
    acc[T] = c;
  }

  // ---- phase 3: s0 = relu(inv_x*acc + drive); D rows r=4lg+reg, col h=16T+l15 ----
  float invxr[4], sxr[4];
  int dirr[4], obr[4];
  #pragma unroll
  for (int reg = 0; reg < 4; ++reg) {
    invxr[reg] = __shfl(inv_x, 4*lg + reg);
    sxr[reg]   = __shfl(sx,    4*lg + reg);
    dirr[reg]  = dirs[rbase + 4*lg + reg];
    obr[reg]   = obs [rbase + 4*lg + reg];
  }
  float s0v[4][4];    // [T][reg]
  float ssg[4] = {0.f,0.f,0.f,0.f}, sgv[4] = {0.f,0.f,0.f,0.f};
  #pragma unroll
  for (int T = 0; T < 4; ++T)
    #pragma unroll
    for (int reg = 0; reg < 4; ++reg) {
      float drive = winT[dirr[reg] * HH + 16*T + l15];
      float v = fmaxf(fmaf(invxr[reg], acc[T][reg], drive), 0.f);
      s0v[T][reg] = v;
      ssg[reg] += v * v; sgv[reg] += v;
    }
  #pragma unroll
  for (int reg = 0; reg < 4; ++reg) {
    #pragma unroll
    for (int m = 1; m < 16; m <<= 1) {
      ssg[reg] += __shfl_xor(ssg[reg], m);
      sgv[reg] += __shfl_xor(sgv[reg], m);
    }
  }
  float invg[4];
  #pragma unroll
  for (int reg = 0; reg < 4; ++reg) invg[reg] = 1.f / (sqrtf(ssg[reg]) + EPSV);
  if (l15 == 0) {
    #pragma unroll
    for (int reg = 0; reg < 4; ++reg) scl0[rbase + 4*lg + reg] = invg[reg];
  }
  float g0 = 0.f;
  if (l15 == 0) {
    #pragma unroll
    for (int reg = 0; reg < 4; ++reg)
      g0 += invxr[reg] * sxr[reg] - invg[reg] * sgv[reg];
  }

  // s0 -> LDS tile ; coalesced buf0 write
  #pragma unroll
  for (int T = 0; T < 4; ++T)
    #pragma unroll
    for (int reg = 0; reg < 4; ++reg)
      s0l[(4*lg + reg) * 68 + 16*T + l15] = s0v[T][reg];
  {
    int rr = l >> 2, cc = (l & 3) * 16;
    const float4* srcl = (const float4*)(s0l + rr * 68 + cc);
    float4* dst = (float4*)(buf0 + (size_t)(rbase + rr) * HH + cc);
    dst[0] = srcl[0]; dst[1] = srcl[1]; dst[2] = srcl[2]; dst[3] = srcl[3];
  }

  // ---- GEMM2: logits = s0 @ WoutT ----
  f16x8 as0, as1;
  {
    const float* pr = s0l + l15 * 68 + lg * 8;
    as0 = ldb8(pr);
    as1 = ldb8(pr + 32);
  }
  f32x4v lac[2];
  #pragma unroll
  for (int T = 0; T < 2; ++T) {
    f32x4v c = {0.f, 0.f, 0.f, 0.f};
    c = MFMA16(as0, bWo[T][0], c);
    c = MFMA16(as1, bWo[T][1], c);
    lac[T] = c;
  }

  // ---- phase 5: softmax + jacobian per row ----
  float jp0[4], jp1[4];
  #pragma unroll
  for (int reg = 0; reg < 4; ++reg) {
    float z0 = lac[0][reg], z1 = lac[1][reg];
    float m = fmaxf(z0, z1);
    #pragma unroll
    for (int mm = 1; mm < 16; mm <<= 1) m = fmaxf(m, __shfl_xor(m, mm));
    float e0 = __expf(invg[reg] * (z0 - m));
    float e1 = __expf(invg[reg] * (z1 - m));
    float se = e0 + e1;
    #pragma unroll
    for (int mm = 1; mm < 16; mm <<= 1) se += __shfl_xor(se, mm);
    float rse = 1.f / se;
    float f0 = e0 * rse, f1 = e1 * rse;
    int ob = obr[reg];
    float on0 = (l15 == ob) ? 1.f : 0.f;
    float on1 = (16 + l15 == ob) ? 1.f : 0.f;
    float fob = on0 * f0 + on1 * f1;
    float sf2 = f0 * f0 + f1 * f1;
    #pragma unroll
    for (int mm = 1; mm < 16; mm <<= 1) {
      fob += __shfl_xor(fob, mm);
      sf2 += __shfl_xor(sf2, mm);
    }
    float fe = fob - sf2;
    jp0[reg] = f0 * (on0 - f0 - fe);
    jp1[reg] = f1 * (on1 - f1 - fe);
  }

  #pragma unroll
  for (int reg = 0; reg < 4; ++reg) {
    jpl[(4*lg + reg) * 36 + l15]      = jp0[reg];
    jpl[(4*lg + reg) * 36 + 16 + l15] = jp1[reg];
  }
  f16x8 ajp;
  {
    const float* pr = jpl + l15 * 36 + lg * 8;
    ajp = ldb8(pr);
  }

  // ---- GEMM3: pv = jp @ Wout ----
  f32x4v pv[4];
  #pragma unroll
  for (int T = 0; T < 4; ++T) {
    f32x4v c = {0.f, 0.f, 0.f, 0.f};
    pv[T] = MFMA16(ajp, bWt[T], c);
  }

  // ---- phase 8: s1 = sv + LR*(s0 - sv + pv); normalize IN PLACE; gates ----
  float ssu[4] = {0.f,0.f,0.f,0.f}, suv[4] = {0.f,0.f,0.f,0.f};
  #pragma unroll
  for (int T = 0; T < 4; ++T)
    #pragma unroll
    for (int reg = 0; reg < 4; ++reg) {
      float s0_ = s0v[T][reg];
      float sv = invg[reg] * s0_;
      float u = fmaf(LR_IT, s0_ - sv + pv[T][reg], sv);
      s0v[T][reg] = u;            // raw s1
      ssu[reg] += u * u; suv[reg] += u;
    }
  #pragma unroll
  for (int reg = 0; reg < 4; ++reg) {
    #pragma unroll
    for (int m = 1; m < 16; m <<= 1) {
      ssu[reg] += __shfl_xor(ssu[reg], m);
      suv[reg] += __shfl_xor(suv[reg], m);
    }
  }
  float invu[4];
  #pragma unroll
  for (int reg = 0; reg < 4; ++reg) invu[reg] = 1.f / (sqrtf(ssu[reg]) + EPSV);
  // buf1 holds NORMALIZED s1 -> effective scale is 1.0 for all downstream consumers
  if (l15 == 0) {
    #pragma unroll
    for (int reg = 0; reg < 4; ++reg) scl1[rbase + 4*lg + reg] = 1.0f;
  }
  float g1 = 0.f;
  if (l15 == 0) {
    #pragma unroll
    for (int reg = 0; reg < 4; ++reg)
      g1 += invg[reg] * sgv[reg] - invu[reg] * suv[reg];
  }
  #pragma unroll
  for (int T = 0; T < 4; ++T)
    #pragma unroll
    for (int reg = 0; reg < 4; ++reg)
      s0v[T][reg] *= invu[reg];   // normalized s1

  // normalized s1 -> LDS tile -> coalesced buf1 (= out s-slice) write
  #pragma unroll
  for (int T = 0; T < 4; ++T)
    #pragma unroll
    for (int reg = 0; reg < 4; ++reg)
      s0l[(4*lg + reg) * 68 + 16*T + l15] = s0v[T][reg];
  {
    int rr = l >> 2, cc = (l & 3) * 16;
    const float4* srcl = (const float4*)(s0l + rr * 68 + cc);
    float4* dst = (float4*)(buf1 + (size_t)(rbase + rr) * HH + cc);
    dst[0] = srcl[0]; dst[1] = srcl[1]; dst[2] = srcl[2]; dst[3] = srcl[3];
  }

  // ---- speculative final: preds = softmax(s1n @ WoutT) -> out[:B*32] ----
  // (correct on the expected act0=1,act1=0 path; improbable paths overwrite)
  {
    const float* pr = s0l + l15 * 68 + lg * 8;
    f16x8 a0 = ldb8(pr);
    f16x8 a1 = ldb8(pr + 32);
    f32x4v pl0 = {0.f,0.f,0.f,0.f}, pl1 = {0.f,0.f,0.f,0.f};
    pl0 = MFMA16(a0, bWo[0][0], pl0); pl0 = MFMA16(a1, bWo[0][1], pl0);
    pl1 = MFMA16(a0, bWo[1][0], pl1); pl1 = MFMA16(a1, bWo[1][1], pl1);
    #pragma unroll
    for (int reg = 0; reg < 4; ++reg) {
      float z0 = pl0[reg], z1 = pl1[reg];
      float m = fmaxf(z0, z1);
      #pragma unroll
      for (int mm = 1; mm < 16; mm <<= 1) m = fmaxf(m, __shfl_xor(m, mm));
      float e0 = __expf(z0 - m), e1 = __expf(z1 - m);
      float se = e0 + e1;
      #pragma unroll
      for (int mm = 1; mm < 16; mm <<= 1) se += __shfl_xor(se, mm);
      float rse = 1.f / se;
      jpl[(4*lg + reg) * 36 + l15]      = e0 * rse;
      jpl[(4*lg + reg) * 36 + 16 + l15] = e1 * rse;
    }
    int rr = l >> 2, cc = (l & 3) * 8;
    const float4* srcl = (const float4*)(jpl + rr * 36 + cc);
    float4* dst = (float4*)(out + (size_t)(rbase + rr) * NOB + cc);
    dst[0] = srcl[0]; dst[1] = srcl[1];
  }

  // ---- gates: wave totals -> block totals ----
  g0 += __shfl_xor(g0, 16); g0 += __shfl_xor(g0, 32);
  g1 += __shfl_xor(g1, 16); g1 += __shfl_xor(g1, 32);
  if (l == 0) { red0[w] = g0; red1[w] = g1; }
  __syncthreads();
  if (t == 0) {
    partials0[blockIdx.x] = red0[0] + red0[1] + red0[2] + red0[3];
    partials1[blockIdx.x] = red1[0] + red1[1] + red1[2] + red1[3];
  }
}

// ---- resolve: decide act0/act1; expected path is a no-op (fused wrote output) ----
__global__ __launch_bounds__(TPB, 2) void resolve_kernel(
    float* __restrict__ buf0, float* __restrict__ buf1,
    float* __restrict__ scl0, float* __restrict__ scl1,
    const float* __restrict__ Wr, const float* __restrict__ Wout,
    const float* __restrict__ Win,
    const int* __restrict__ dirs, const int* __restrict__ obs,
    const float* __restrict__ partials0, float* __restrict__ partials,
    int* __restrict__ actArr, float* __restrict__ out)
{
  __shared__ float wrl[HH * WRS];
  __shared__ float wot[HH * WOS];
  __shared__ float wint[NDIRS * WRS];
  __shared__ float red[4];
  int t = threadIdx.x;

  float t0v = gate_reduce_nbf(partials0, red, t);
  int act0 = (fabsf(t0v * INV_BH) > TOLV) ? 1 : 0;
  float t1v = gate_reduce_nbf(partials, red, t);
  int act1 = (fabsf(t1v * INV_BH) > TOLV) ? 1 : 0;
  if (blockIdx.x == 0 && t == 0) actArr[1] = act0 && act1;

  int r = blockIdx.x * TPB + t;

  if (!act0) {
    // iteration 0 inactive: final = s0 (overwrite speculative s1 output)
    if (t < 4) partials[blockIdx.x * 4 + t] = partials0[blockIdx.x * 4 + t];
    stage_wot(Wout, wot, t, TPB);
    __syncthreads();
    final_write(r, scl0[r], buf0, out, wot);
    return;
  }
  if (!act1) return;   // EXPECTED PATH: fused already wrote preds + normalized s1

  // both active: run iteration 1 fully. S=buf1 (normalized, scl1==1), P=buf0, W=buf0/scl0.
  stage_wr(Wr, wrl, t, TPB);
  stage_wot(Wout, wot, t, TPB);
  stage_wint(Win, wint, t, TPB);
  __syncthreads();

  float a_s = scl1[r];
  float a_p = scl0[r];
  int ob = obs[r];
  int dir = dirs[r];
  const float4* __restrict__ sr4 = (const float4*)(buf1 + (size_t)r * HH);

  float zz[NOB];
  #pragma unroll
  for (int o = 0; o < NOB; ++o) zz[o] = 0.f;
  float sS = 0.f;
  #pragma unroll 1
  for (int h0 = 0; h0 < 16; ++h0) {
    float4 s4 = sr4[h0];
    sS += SUM4(s4);
    const float* t0 = &wot[(h0 * 4 + 0) * WOS];
    const float* t1 = &wot[(h0 * 4 + 1) * WOS];
    const float* t2 = &wot[(h0 * 4 + 2) * WOS];
    const float* t3 = &wot[(h0 * 4 + 3) * WOS];
    #pragma unroll
    for (int o = 0; o < NOB; ++o)
      zz[o] += s4.x * t0[o] + s4.y * t1[o] + s4.z * t2[o] + s4.w * t3[o];
  }
  SOFTJP(zz, a_s, ob)
  __syncthreads();   // live-range firewall

  const float4* __restrict__ pr4 = (const float4*)(buf0 + (size_t)r * HH);
  LOADP(pr4);
  float4* wo4 = (float4*)(buf0 + (size_t)r * HH);
  float ssu = 0.f, su = 0.f;
#define STEP_C_ONE(JJ, COMP) { \
    const float* wr_ = &wrl[(h0 * 4 + JJ) * WRS]; \
    float g_ = fmaxf(fmaf(a_p, DOT64P(wr_), d4.COMP), 0.f); \
    const float* wt_ = &wot[(h0 * 4 + JJ) * WOS]; \
    float w_ = 0.f; \
    _Pragma("unroll") \
    for (int o = 0; o < NOB; ++o) w_ += zz[o] * wt_[o]; \
    float sv_ = a_s * s4.COMP; \
    float uu_ = fmaf(LR_IT, g_ - sv_ + w_, sv_); \
    u.COMP = uu_; ssu += uu_ * uu_; su += uu_; }
  #pragma unroll 1
  for (int h0 = 0; h0 < 16; ++h0) {
    float4 s4 = sr4[h0];
    float4 d4 = *(const float4*)&wint[dir * WRS + h0 * 4];
    float4 u;
    STEP_C_ONE(0, x) STEP_C_ONE(1, y) STEP_C_ONE(2, z) STEP_C_ONE(3, w)
    wo4[h0] = u;
  }
  float inv_u = 1.f / (sqrtf(ssu) + EPSV);
  scl0[r] = inv_u;

  float tot2 = block_reduce_all(a_s * sS - inv_u * su, red, t);
  if (t == 0) partials[blockIdx.x] = tot2;
  if (t == 1) partials[blockIdx.x + NBLK] = 0.f;
  if (t == 2) partials[blockIdx.x + 2 * NBLK] = 0.f;
  if (t == 3) partials[blockIdx.x + 3 * NBLK] = 0.f;
}

// ---- generic step k>=2: gate + (active | first-inactive final | no-op) ----
__global__ __launch_bounds__(TPB, 2) void step_kernel(
    float* __restrict__ buf0, float* __restrict__ buf1,
    float* __restrict__ scl0, float* __restrict__ scl1,
    const float* __restrict__ Wr, const float* __restrict__ Wout,
    const float* __restrict__ Win,
    const int* __restrict__ dirs, const int* __restrict__ obs,
    float* __restrict__ partials, int* __restrict__ actArr,
    float* __restrict__ out, int k)
{
  __shared__ float red[4];
  __shared__ float wrl[HH * WRS];
  __shared__ float wot[HH * WOS];
  __shared__ float wint[NDIRS * WRS];
  int t = threadIdx.x;

  float tot = gate_reduce_nbf(partials, red, t);
  int active = (fabsf(tot * INV_BH) > TOLV) ? 1 : 0;
  if (blockIdx.x == 0 && t == 0) actArr[k] = active;

  int si = k & 1;
  int r = blockIdx.x * TPB + t;

  if (!active) {
    int first_inactive = actArr[k - 1];
    if (!first_inactive) return;
    stage_wot(Wout, wot, t, TPB);
    __syncthreads();
    const float* S   = si ? buf1 : buf0;
    const float* scl = si ? scl1 : scl0;
    final_write(r, scl[r], S, out, wot);
    return;
  }

  const float* S    = si ? buf1 : buf0;
  const float* sclS = si ? scl1 : scl0;
  float* W          = si ? buf0 : buf1;
  float* sclW       = si ? scl0 : scl1;

  stage_wr(Wr, wrl, t, TPB);
  stage_wot(Wout, wot, t, TPB);
  stage_wint(Win, wint, t, TPB);
  __syncthreads();

  float a_s = sclS[r];
  float a_p = sclW[r];
  int ob = obs[r];
  int dir = dirs[r];
  const float4* __restrict__ sr4 = (const float4*)(S + (size_t)r * HH);

  float zz[NOB];
  #pragma unroll
  for (int o = 0; o < NOB; ++o) zz[o] = 0.f;
  float sS = 0.f;
  #pragma unroll 1
  for (int h0 = 0; h0 < 16; ++h0) {
    float4 s4 = sr4[h0];
    sS += SUM4(s4);
    const float* t0 = &wot[(h0 * 4 + 0) * WOS];
    const float* t1 = &wot[(h0 * 4 + 1) * WOS];
    const float* t2 = &wot[(h0 * 4 + 2) * WOS];
    const float* t3 = &wot[(h0 * 4 + 3) * WOS];
    #pragma unroll
    for (int o = 0; o < NOB; ++o)
      zz[o] += s4.x * t0[o] + s4.y * t1[o] + s4.z * t2[o] + s4.w * t3[o];
  }
  SOFTJP(zz, a_s, ob)
  __syncthreads();

  const float4* __restrict__ pr4 = (const float4*)(W + (size_t)r * HH);
  LOADP(pr4);
  float4* wo4 = (float4*)(W + (size_t)r * HH);
  float ssu = 0.f, su = 0.f;
  #pragma unroll 1
  for (int h0 = 0; h0 < 16; ++h0) {
    float4 s4 = sr4[h0];
    float4 d4 = *(const float4*)&wint[dir * WRS + h0 * 4];
    float4 u;
    STEP_C_ONE(0, x) STEP_C_ONE(1, y) STEP_C_ONE(2, z) STEP_C_ONE(3, w)
    wo4[h0] = u;
  }
  float inv_u = 1.f / (sqrtf(ssu) + EPSV);
  sclW[r] = inv_u;

  float tot2 = block_reduce_all(a_s * sS - inv_u * su, red, t);
  if (t == 0) partials[blockIdx.x] = tot2;
  if (t == 1) partials[blockIdx.x + NBLK] = 0.f;
  if (t == 2) partials[blockIdx.x + 2 * NBLK] = 0.f;
  if (t == 3) partials[blockIdx.x + 3 * NBLK] = 0.f;
}

// ---- tail: only fires when all 10 iterations were active ----
__global__ __launch_bounds__(TPB, 2) void final_kernel(
    const float* __restrict__ buf0, float* __restrict__ out,
    const float* __restrict__ scl0,
    const float* __restrict__ Wout, const int* __restrict__ actArr)
{
  if (actArr[9] == 0) return;
  __shared__ float wot[HH * WOS];
  int t = threadIdx.x;
  stage_wot(Wout, wot, t, TPB);
  __syncthreads();
  int r = blockIdx.x * TPB + t;
  final_write(r, scl0[r], buf0, out, wot);
}

extern "C" void kernel_launch(void* const* d_in, const int* in_sizes, int n_in,
                              void* d_out, int out_size, void* d_ws, size_t ws_size,
                              hipStream_t stream) {
  const int* dirs = (const int*)d_in[0];
  const int* obs = (const int*)d_in[1];
  const float* x = (const float*)d_in[2];
  const float* Wr = (const float*)d_in[3];
  const float* Win = (const float*)d_in[4];
  const float* Wout = (const float*)d_in[5];
  float* out = (float*)d_out;
  float* ws = (float*)d_ws;

  float* buf0 = ws;                              // B*H raw state s0 (then s2,..)
  float* scl0 = ws + (size_t)BB * HH;            // B
  float* scl1 = scl0 + BB;                       // B
  float* partials = scl1 + BB;                   // NBF (gate for "current" iteration)
  float* partials0 = partials + NBF;             // NBF (gate0)
  int* actArr = (int*)(partials0 + NBF);         // 16 ints
  float* wotT = (float*)(actArr + 16);           // 64*32
  float* winT = wotT + NOB * HH;                 // 8*64
  float* buf1 = out + (size_t)BB * NOB;          // s-slice of d_out: s1 (normalized)

  prep_kernel<<<1, TPB, 0, stream>>>(Wout, Win, wotT, winT);
  fused_kernel<<<NBF, TPB, 0, stream>>>(x, dirs, obs, Wr, Wout, wotT, winT,
                                        buf0, buf1, scl0, scl1, partials0, partials, out);
  resolve_kernel<<<NBLK, TPB, 0, stream>>>(buf0, buf1, scl0, scl1, Wr, Wout, Win,
                                           dirs, obs, partials0, partials, actArr, out);
  for (int k = 2; k < 10; ++k)
    step_kernel<<<NBLK, TPB, 0, stream>>>(buf0, buf1, scl0, scl1,
                                          Wr, Wout, Win, dirs, obs, partials, actArr, out, k);
  final_kernel<<<NBLK, TPB, 0, stream>>>(buf0, out, scl0, Wout, actArr);
}